// Round 2
// baseline (11272.638 us; speedup 1.0000x reference)
//
#include <hip/hip_runtime.h>
#include <hip/hip_bf16.h>

// MultiVForecaster: 4-layer Mamba over (B=16, L=1024, D=512), ED=1024, N=16,
// DR=32, DC=4, then head -> (B, 32, 96). f32 baseline, adaptive-chunked
// workspace (33.5MB + cb*14.94MB, cb in {16,8,4,2,1}).

#define B_ 16
#define L_ 1024
#define D_ 512
#define ED_ 1024
#define N_ 16
#define DR_ 32
#define DC_ 4
#define BL_ (B_ * L_)

// ---------------------------------------------------------------- embed
// h[b,l,d] = sum_i x[b,i,l] * embed_w[d,i] + embed_b[d]
__global__ __launch_bounds__(256) void embed_kernel(
    const float* __restrict__ x, const float* __restrict__ w,
    const float* __restrict__ bias, float* __restrict__ h) {
  int bl = blockIdx.x;              // b*L + l
  int b = bl >> 10, l = bl & 1023;
  __shared__ float xs[32];
  if (threadIdx.x < 32) xs[threadIdx.x] = x[(b * 32 + threadIdx.x) * 1024 + l];
  __syncthreads();
  for (int d = threadIdx.x; d < D_; d += 256) {
    float s = bias[d];
#pragma unroll
    for (int i = 0; i < 32; ++i) s = fmaf(xs[i], w[d * 32 + i], s);
    h[(size_t)bl * D_ + d] = s;
  }
}

// ---------------------------------------------------------------- rmsnorm
__global__ __launch_bounds__(256) void rmsnorm_kernel(
    const float* __restrict__ h, const float* __restrict__ w,
    float* __restrict__ hn) {
  int row = blockIdx.x;  // chunk-local row
  const float* p = h + (size_t)row * D_;
  float v0 = p[threadIdx.x], v1 = p[threadIdx.x + 256];
  float ss = v0 * v0 + v1 * v1;
#pragma unroll
  for (int o = 32; o; o >>= 1) ss += __shfl_down(ss, o);
  __shared__ float red[4];
  if ((threadIdx.x & 63) == 0) red[threadIdx.x >> 6] = ss;
  __syncthreads();
  float tot = red[0] + red[1] + red[2] + red[3];
  float scale = rsqrtf(tot * (1.f / D_) + 1e-5f);
  hn[(size_t)row * D_ + threadIdx.x] = v0 * scale * w[threadIdx.x];
  hn[(size_t)row * D_ + threadIdx.x + 256] = v1 * scale * w[threadIdx.x + 256];
}

// ---------------------------------------------------------------- GEMM
// C[m,n] = sum_k A[m,k] * W[n,k]  (+ epilogue)
// EPI: 0 = store, 1 = C += (residual add), 2 = softplus(v + bias[n])
template <int BN, int EPI>
__global__ __launch_bounds__(256) void gemm_kernel(
    const float* __restrict__ A, int lda, const float* __restrict__ W,
    float* __restrict__ C, int ldc, const float* __restrict__ bias, int M,
    int N, int K) {
  constexpr int BM = 128, BK = 8;
  constexpr int TM = 8, TN = BN / 16;
  __shared__ float As[BK][BM + 4];
  __shared__ float Ws[BK][BN + 4];
  const int tid = threadIdx.x;
  const int m0 = blockIdx.y * BM;
  const int n0 = blockIdx.x * BN;
  const int tm = tid >> 4, tn = tid & 15;

  float acc[TM][TN];
#pragma unroll
  for (int r = 0; r < TM; ++r)
#pragma unroll
    for (int c = 0; c < TN; ++c) acc[r][c] = 0.f;

  for (int k0 = 0; k0 < K; k0 += BK) {
    // A tile: 128 rows x 8 cols = 256 float4, one per thread
    {
      int m = tid >> 1, kq = (tid & 1) << 2;
      float4 v = *(const float4*)(A + (size_t)(m0 + m) * lda + k0 + kq);
      As[kq + 0][m] = v.x;
      As[kq + 1][m] = v.y;
      As[kq + 2][m] = v.z;
      As[kq + 3][m] = v.w;
    }
    // W tile: BN rows x 8 cols
    for (int i = tid; i < BN * 2; i += 256) {
      int n = i >> 1, kq = (i & 1) << 2;
      float4 v = make_float4(0.f, 0.f, 0.f, 0.f);
      if (n0 + n < N) v = *(const float4*)(W + (size_t)(n0 + n) * K + k0 + kq);
      Ws[kq + 0][n] = v.x;
      Ws[kq + 1][n] = v.y;
      Ws[kq + 2][n] = v.z;
      Ws[kq + 3][n] = v.w;
    }
    __syncthreads();
#pragma unroll
    for (int k = 0; k < BK; ++k) {
      float a[TM], b[TN];
#pragma unroll
      for (int r = 0; r < TM; ++r) a[r] = As[k][tm * TM + r];
#pragma unroll
      for (int c = 0; c < TN; ++c) b[c] = Ws[k][tn * TN + c];
#pragma unroll
      for (int r = 0; r < TM; ++r)
#pragma unroll
        for (int c = 0; c < TN; ++c) acc[r][c] = fmaf(a[r], b[c], acc[r][c]);
    }
    __syncthreads();
  }

#pragma unroll
  for (int r = 0; r < TM; ++r) {
    int gm = m0 + tm * TM + r;
#pragma unroll
    for (int c = 0; c < TN; ++c) {
      int gn = n0 + tn * TN + c;
      if (gn < N) {
        float v = acc[r][c];
        if (EPI == 1) v += C[(size_t)gm * ldc + gn];
        if (EPI == 2) {
          v += bias[gn];
          v = (v > 20.f) ? v : log1pf(expf(v));
        }
        C[(size_t)gm * ldc + gn] = v;
      }
    }
  }
}

// ---------------------------------------------------------------- conv+silu
// out[bl,ed] = silu( sum_j xcr[bl-3+j, ed] * cw[ed,j] + cb[ed] ), causal per b
__global__ __launch_bounds__(256) void conv_silu_kernel(
    const float* __restrict__ xcr, const float* __restrict__ cw,
    const float* __restrict__ cb, float* __restrict__ out) {
  int idx = blockIdx.x * 256 + threadIdx.x;  // bl*ED + ed (chunk-local)
  int ed = idx & 1023;
  int bl = idx >> 10;
  int l = bl & 1023;  // time within batch
  float s = cb[ed];
#pragma unroll
  for (int j = 0; j < DC_; ++j) {
    int ll = l - 3 + j;
    if (ll >= 0)
      s = fmaf(xcr[(size_t)(bl - 3 + j) * 1024 + ed], cw[ed * 4 + j], s);
  }
  out[idx] = s / (1.f + expf(-s));
}

// ---------------------------------------------------------------- SSM scan
// One thread per (b, ed, n) state; 16-lane reduce over n; gating fused.
// y written in-place over dly (the delta buffer).
__global__ __launch_bounds__(256) void scan_kernel(
    float* dly,                       // delta in, y out (aliased!)
    const float* __restrict__ dbc,    // (bc,L,64): [delta(32) | B(16) | C(16)]
    const float* __restrict__ xc,     // (bc,L,ED) post conv+silu
    const float* __restrict__ z,      // (bc,L,ED) gate
    const float* __restrict__ A_log,  // (ED,16)
    const float* __restrict__ Dp) {   // (ED)
  const int tid = threadIdx.x;
  const int n = tid & 15, edl = tid >> 4;  // edl 0..15
  const int b = blockIdx.x >> 6;           // chunk-local batch
  const int edg = blockIdx.x & 63;
  const int ed = edg * 16 + edl;
  const float An = -expf(A_log[ed * 16 + n]);
  const float Dv = Dp[ed];
  float hst = 0.f;
  int aidx = b * (L_ * ED_) + ed;
  int didx = b * (L_ * 64) + 32 + n;
  for (int l = 0; l < L_; ++l) {
    float dlt = dly[aidx];
    float u = xc[aidx];
    float Bn = dbc[didx];
    float Cn = dbc[didx + 16];
    float dA = expf(dlt * An);
    hst = fmaf(dA, hst, dlt * u * Bn);
    float py = hst * Cn;
    py += __shfl_xor(py, 1);
    py += __shfl_xor(py, 2);
    py += __shfl_xor(py, 4);
    py += __shfl_xor(py, 8);
    if (n == 0) {
      float zz = z[aidx];
      float sig = 1.f / (1.f + expf(-zz));
      dly[aidx] = (py + Dv * u) * (zz * sig);
    }
    aidx += ED_;
    didx += 64;
  }
}

// ---------------------------------------------------------------- head
// out[b, c, t] = sum_d h[b,1023,d]*head_w[t*32+c, d] + head_b[t*32+c]
__global__ __launch_bounds__(256) void head_kernel(
    const float* __restrict__ h, const float* __restrict__ hw,
    const float* __restrict__ hb, float* __restrict__ out) {
  int hc = blockIdx.x * 256 + threadIdx.x;  // 0..3071
  int b = blockIdx.y;
  __shared__ float hs[D_];
  for (int d = threadIdx.x; d < D_; d += 256)
    hs[d] = h[((size_t)(b << 10) + 1023) * D_ + d];
  __syncthreads();
  float s = hb[hc];
#pragma unroll 8
  for (int d = 0; d < D_; ++d) s = fmaf(hs[d], hw[(size_t)hc * D_ + d], s);
  int t = hc >> 5, c = hc & 31;
  out[(size_t)b * 3072 + c * 96 + t] = s;
}

// ---------------------------------------------------------------- launch
extern "C" void kernel_launch(void* const* d_in, const int* in_sizes, int n_in,
                              void* d_out, int out_size, void* d_ws,
                              size_t ws_size, hipStream_t stream) {
  const float* x = (const float*)d_in[0];
  const float* embed_w = (const float*)d_in[1];
  const float* embed_b = (const float*)d_in[2];
  const float* norm_w = (const float*)d_in[3];
  const float* in_proj_w = (const float*)d_in[4];
  const float* conv_w = (const float*)d_in[5];
  const float* conv_b = (const float*)d_in[6];
  const float* x_proj_w = (const float*)d_in[7];
  const float* dt_proj_w = (const float*)d_in[8];
  const float* dt_proj_b = (const float*)d_in[9];
  const float* A_log = (const float*)d_in[10];
  const float* Dp = (const float*)d_in[11];
  const float* out_proj_w = (const float*)d_in[12];
  const float* head_w = (const float*)d_in[13];
  const float* head_b = (const float*)d_in[14];
  float* out = (float*)d_out;

  // Workspace: h (persistent, 33.5MB) + per-chunk buffers.
  // Per 1024 rows: hn 512 + xcr 1024 + z 1024 + xcs 1024 + dbc 64 floats.
  const size_t hbytes = (size_t)BL_ * D_ * 4;
  const size_t rowb = (size_t)(512 + 1024 + 1024 + 1024 + 64) * 4;  // /row
  int cb = 16;  // batches per chunk
  while (cb > 1 && hbytes + (size_t)cb * 1024 * rowb > ws_size) cb >>= 1;
  if (hbytes + (size_t)cb * 1024 * rowb > ws_size) return;  // impossible

  float* ws = (float*)d_ws;
  float* h = ws;                                  // BL * 512 (persistent)
  float* hn = h + (size_t)BL_ * D_;               // cb*1024 * 512
  float* xcr = hn + (size_t)cb * 1024 * 512;      // cb*1024 * 1024 (also dlt/y)
  float* zb = xcr + (size_t)cb * 1024 * 1024;     // cb*1024 * 1024
  float* xcs = zb + (size_t)cb * 1024 * 1024;     // cb*1024 * 1024
  float* dbc = xcs + (size_t)cb * 1024 * 1024;    // cb*1024 * 64

  embed_kernel<<<BL_, 256, 0, stream>>>(x, embed_w, embed_b, h);

  const int nchunks = 16 / cb;
  const int Mc = cb * 1024;  // rows per chunk
  for (int i = 0; i < 4; ++i) {
    const float* ipw = in_proj_w + (size_t)i * 2 * ED_ * D_;
    for (int ch = 0; ch < nchunks; ++ch) {
      float* hc = h + (size_t)ch * Mc * D_;
      rmsnorm_kernel<<<Mc, 256, 0, stream>>>(hc, norm_w + i * D_, hn);
      // xc_raw = hn @ in_w[0:1024]^T ; z = hn @ in_w[1024:2048]^T
      gemm_kernel<128, 0><<<dim3(8, Mc / 128), 256, 0, stream>>>(
          hn, D_, ipw, xcr, ED_, nullptr, Mc, ED_, D_);
      gemm_kernel<128, 0><<<dim3(8, Mc / 128), 256, 0, stream>>>(
          hn, D_, ipw + (size_t)ED_ * D_, zb, ED_, nullptr, Mc, ED_, D_);
      conv_silu_kernel<<<(Mc * ED_) / 256, 256, 0, stream>>>(
          xcr, conv_w + i * ED_ * DC_, conv_b + i * ED_, xcs);
      // dbc = xcs @ x_proj^T : (Mc,1024)x(1024,64)
      gemm_kernel<16, 0><<<dim3(4, Mc / 128), 256, 0, stream>>>(
          xcs, ED_, x_proj_w + (size_t)i * 64 * ED_, dbc, 64, nullptr, Mc, 64,
          ED_);
      // delta = softplus(dbc[:, :32] @ dt^T + dt_b) -> overwrites xcr
      gemm_kernel<128, 2><<<dim3(8, Mc / 128), 256, 0, stream>>>(
          dbc, 64, dt_proj_w + (size_t)i * ED_ * DR_, xcr, ED_,
          dt_proj_b + i * ED_, Mc, ED_, DR_);
      scan_kernel<<<cb * 64, 256, 0, stream>>>(
          xcr, dbc, xcs, zb, A_log + (size_t)i * ED_ * N_, Dp + i * ED_);
      // h += y @ out_proj^T
      gemm_kernel<128, 1><<<dim3(4, Mc / 128), 256, 0, stream>>>(
          xcr, ED_, out_proj_w + (size_t)i * D_ * ED_, hc, D_, nullptr, Mc, D_,
          ED_);
    }
  }

  head_kernel<<<dim3(12, B_), 256, 0, stream>>>(h, head_w, head_b, out);
}

// Round 3
// 4383.258 us; speedup vs baseline: 2.5717x; 2.5717x over previous
//
#include <hip/hip_runtime.h>
#include <hip/hip_bf16.h>

// MultiVForecaster: 4-layer Mamba (B=16, L=1024, D=512, ED=1024, N=16).
// Round 3: bf16 MFMA GEMMs for in/out_proj + LDS-tiled SSM scan.

#define B_ 16
#define L_ 1024
#define D_ 512
#define ED_ 1024
#define N_ 16
#define DR_ 32
#define DC_ 4
#define BL_ (B_ * L_)

typedef __attribute__((ext_vector_type(8))) __bf16 bf16x8;
typedef __attribute__((ext_vector_type(4))) float f32x4;

#define ASYNC_LDS16(G, L)                                                      \
  __builtin_amdgcn_global_load_lds(                                            \
      (const __attribute__((address_space(1))) void*)(G),                      \
      (__attribute__((address_space(3))) void*)(L), 16, 0, 0)

// ---------------------------------------------------------------- embed
__global__ __launch_bounds__(256) void embed_kernel(
    const float* __restrict__ x, const float* __restrict__ w,
    const float* __restrict__ bias, float* __restrict__ h) {
  int bl = blockIdx.x;
  int b = bl >> 10, l = bl & 1023;
  __shared__ float xs[32];
  if (threadIdx.x < 32) xs[threadIdx.x] = x[(b * 32 + threadIdx.x) * 1024 + l];
  __syncthreads();
  for (int d = threadIdx.x; d < D_; d += 256) {
    float s = bias[d];
#pragma unroll
    for (int i = 0; i < 32; ++i) s = fmaf(xs[i], w[d * 32 + i], s);
    h[(size_t)bl * D_ + d] = s;
  }
}

// ---------------------------------------------------------------- cvt f32->bf16
__global__ __launch_bounds__(256) void cvt_bf16_kernel(
    const float* __restrict__ src, __hip_bfloat16* __restrict__ dst, int n4) {
  int i = blockIdx.x * 256 + threadIdx.x;
  if (i < n4) {
    float4 v = *(const float4*)&src[(size_t)i * 4];
    __hip_bfloat16 t4[4] = {__float2bfloat16(v.x), __float2bfloat16(v.y),
                            __float2bfloat16(v.z), __float2bfloat16(v.w)};
    *(ushort4*)&dst[(size_t)i * 4] = *(ushort4*)t4;
  }
}

// ---------------------------------------------------------------- rmsnorm -> bf16
__global__ __launch_bounds__(256) void rmsnorm_kernel(
    const float* __restrict__ h, const float* __restrict__ w,
    __hip_bfloat16* __restrict__ hn) {
  int row = blockIdx.x;
  const float* p = h + (size_t)row * D_;
  float v0 = p[threadIdx.x], v1 = p[threadIdx.x + 256];
  float ss = v0 * v0 + v1 * v1;
#pragma unroll
  for (int o = 32; o; o >>= 1) ss += __shfl_down(ss, o);
  __shared__ float red[4];
  if ((threadIdx.x & 63) == 0) red[threadIdx.x >> 6] = ss;
  __syncthreads();
  float tot = red[0] + red[1] + red[2] + red[3];
  float scale = rsqrtf(tot * (1.f / D_) + 1e-5f);
  hn[(size_t)row * D_ + threadIdx.x] =
      __float2bfloat16(v0 * scale * w[threadIdx.x]);
  hn[(size_t)row * D_ + threadIdx.x + 256] =
      __float2bfloat16(v1 * scale * w[threadIdx.x + 256]);
}

// ---------------------------------------------------------------- MFMA GEMM
// C[m,n] = sum_k A[m,k] * W[n,k]; A,W bf16 K-contiguous; C f32.
// EPI: 0 = store, 1 = C +=
// 128x128 tile, 4 waves (each 64x64 = 4x4 frags of 16x16x32), BK=32.
// LDS holds fragment-ordered tiles: frag f = 64 lanes x 16B, so ds_read_b128
// at frag_base + lane*16 is conflict-free and global_load_lds dest is linear.
template <int EPI>
__global__ __launch_bounds__(256) void gemm_mfma_kernel(
    const __hip_bfloat16* __restrict__ A, int lda,
    const __hip_bfloat16* __restrict__ W, float* __restrict__ C, int ldc,
    int K) {
  __shared__ __bf16 As[2][4096];
  __shared__ __bf16 Bs[2][4096];
  const int tid = threadIdx.x;
  const int w = tid >> 6, l = tid & 63;
  const int m0 = blockIdx.y * 128, n0 = blockIdx.x * 128;
  const int wr = w >> 1, wc = w & 1;
  const int lrow = l & 15, lk = (l >> 4) * 8;

  const size_t arow0 = (size_t)(m0 + w * 16 + lrow) * lda + lk;
  const size_t arow1 = (size_t)(m0 + (w + 4) * 16 + lrow) * lda + lk;
  const size_t brow0 = (size_t)(n0 + w * 16 + lrow) * K + lk;
  const size_t brow1 = (size_t)(n0 + (w + 4) * 16 + lrow) * K + lk;

  f32x4 acc[4][4];
#pragma unroll
  for (int i = 0; i < 4; ++i)
#pragma unroll
    for (int j = 0; j < 4; ++j) acc[i][j] = (f32x4)0.f;

  auto stage = [&](int bufi, int k0) {
    ASYNC_LDS16(A + arow0 + k0, &As[bufi][w * 512]);
    ASYNC_LDS16(A + arow1 + k0, &As[bufi][(w + 4) * 512]);
    ASYNC_LDS16(W + brow0 + k0, &Bs[bufi][w * 512]);
    ASYNC_LDS16(W + brow1 + k0, &Bs[bufi][(w + 4) * 512]);
  };

  stage(0, 0);
  int buf = 0;
  for (int k0 = 0; k0 < K; k0 += 32) {
    __syncthreads();
    if (k0 + 32 < K) stage(buf ^ 1, k0 + 32);
    bf16x8 af[4], bfr[4];
#pragma unroll
    for (int mi = 0; mi < 4; ++mi)
      af[mi] = *(bf16x8*)&As[buf][(wr * 4 + mi) * 512 + l * 8];
#pragma unroll
    for (int ni = 0; ni < 4; ++ni)
      bfr[ni] = *(bf16x8*)&Bs[buf][(wc * 4 + ni) * 512 + l * 8];
#pragma unroll
    for (int mi = 0; mi < 4; ++mi)
#pragma unroll
      for (int ni = 0; ni < 4; ++ni)
        acc[mi][ni] = __builtin_amdgcn_mfma_f32_16x16x32_bf16(
            af[mi], bfr[ni], acc[mi][ni], 0, 0, 0);
    buf ^= 1;
  }

#pragma unroll
  for (int mi = 0; mi < 4; ++mi) {
#pragma unroll
    for (int ni = 0; ni < 4; ++ni) {
      int row = m0 + wr * 64 + mi * 16 + (l >> 4) * 4;
      int col = n0 + wc * 64 + ni * 16 + (l & 15);
      float* cp = C + (size_t)row * ldc + col;
#pragma unroll
      for (int r = 0; r < 4; ++r) {
        float v = acc[mi][ni][r];
        if (EPI == 1) v += cp[(size_t)r * ldc];
        cp[(size_t)r * ldc] = v;
      }
    }
  }
}

// ---------------------------------------------------------------- f32 GEMM (small)
template <int BN, int EPI>  // EPI 2 = softplus(v + bias[n])
__global__ __launch_bounds__(256) void gemm_kernel(
    const float* __restrict__ A, int lda, const float* __restrict__ W,
    float* __restrict__ C, int ldc, const float* __restrict__ bias, int M,
    int N, int K) {
  constexpr int BM = 128, BK = 8;
  constexpr int TM = 8, TN = BN / 16;
  __shared__ float As[BK][BM + 4];
  __shared__ float Ws[BK][BN + 4];
  const int tid = threadIdx.x;
  const int m0 = blockIdx.y * BM;
  const int n0 = blockIdx.x * BN;
  const int tm = tid >> 4, tn = tid & 15;

  float acc[TM][TN];
#pragma unroll
  for (int r = 0; r < TM; ++r)
#pragma unroll
    for (int c = 0; c < TN; ++c) acc[r][c] = 0.f;

  for (int k0 = 0; k0 < K; k0 += BK) {
    {
      int m = tid >> 1, kq = (tid & 1) << 2;
      float4 v = *(const float4*)(A + (size_t)(m0 + m) * lda + k0 + kq);
      As[kq + 0][m] = v.x;
      As[kq + 1][m] = v.y;
      As[kq + 2][m] = v.z;
      As[kq + 3][m] = v.w;
    }
    for (int i = tid; i < BN * 2; i += 256) {
      int n = i >> 1, kq = (i & 1) << 2;
      float4 v = make_float4(0.f, 0.f, 0.f, 0.f);
      if (n0 + n < N) v = *(const float4*)(W + (size_t)(n0 + n) * K + k0 + kq);
      Ws[kq + 0][n] = v.x;
      Ws[kq + 1][n] = v.y;
      Ws[kq + 2][n] = v.z;
      Ws[kq + 3][n] = v.w;
    }
    __syncthreads();
#pragma unroll
    for (int k = 0; k < BK; ++k) {
      float a[TM], b[TN];
#pragma unroll
      for (int r = 0; r < TM; ++r) a[r] = As[k][tm * TM + r];
#pragma unroll
      for (int c = 0; c < TN; ++c) b[c] = Ws[k][tn * TN + c];
#pragma unroll
      for (int r = 0; r < TM; ++r)
#pragma unroll
        for (int c = 0; c < TN; ++c) acc[r][c] = fmaf(a[r], b[c], acc[r][c]);
    }
    __syncthreads();
  }

#pragma unroll
  for (int r = 0; r < TM; ++r) {
    int gm = m0 + tm * TM + r;
#pragma unroll
    for (int c = 0; c < TN; ++c) {
      int gn = n0 + tn * TN + c;
      if (gn < N) {
        float v = acc[r][c];
        if (EPI == 2) {
          v += bias[gn];
          v = (v > 20.f) ? v : log1pf(expf(v));
        }
        C[(size_t)gm * ldc + gn] = v;
      }
    }
  }
}

// ---------------------------------------------------------------- conv+silu
__global__ __launch_bounds__(256) void conv_silu_kernel(
    const float* __restrict__ xcr, const float* __restrict__ cw,
    const float* __restrict__ cb, float* __restrict__ out) {
  int idx = blockIdx.x * 256 + threadIdx.x;
  int ed = idx & 1023;
  int bl = idx >> 10;
  int l = bl & 1023;
  float s = cb[ed];
#pragma unroll
  for (int j = 0; j < DC_; ++j) {
    int ll = l - 3 + j;
    if (ll >= 0)
      s = fmaf(xcr[(size_t)(bl - 3 + j) * 1024 + ed], cw[ed * 4 + j], s);
  }
  out[idx] = s / (1.f + expf(-s));
}

// ---------------------------------------------------------------- SSM scan v2
// Block = (b, 32-ed slice); thread owns (ed, n-pair); LDS double-buffered
// tiles of T=32 timesteps; serial chain is 1 fma/state/step; y out bf16.
__global__ __launch_bounds__(256) void scan2_kernel(
    const float* __restrict__ dlt, const float* __restrict__ dbc,
    const float* __restrict__ xc, const float* __restrict__ zg,
    const float* __restrict__ A_log, const float* __restrict__ Dp,
    __hip_bfloat16* __restrict__ y) {
  const int tid = threadIdx.x;
  const int edl = tid >> 3, np = tid & 7, n0 = np * 2;
  const int b = blockIdx.x >> 5, edg = blockIdx.x & 31;
  const int edbase = edg * 32, ed = edbase + edl;
  __shared__ float sd[2][32][32], sx[2][32][32], sz[2][32][32], sbc[2][32][32];
  __shared__ float sy[32][32];
  const float An0 = -__expf(A_log[ed * 16 + n0]);
  const float An1 = -__expf(A_log[ed * 16 + n0 + 1]);
  const float Dv = Dp[ed];
  float h0 = 0.f, h1 = 0.f;
  const int sr = tid >> 3, sc = (tid & 7) * 4;  // staging row/col4
  const int w8 = (tid >> 6) * 8;                // wave's 8-row LDS base
  const size_t rb = (size_t)b * 1024;

  auto stage = [&](int bufi, int tl) {
    size_t row = rb + (size_t)tl * 32 + sr;
    ASYNC_LDS16(&dlt[row * 1024 + edbase + sc], &sd[bufi][w8][0]);
    ASYNC_LDS16(&xc[row * 1024 + edbase + sc], &sx[bufi][w8][0]);
    ASYNC_LDS16(&zg[row * 1024 + edbase + sc], &sz[bufi][w8][0]);
    ASYNC_LDS16(&dbc[row * 64 + 32 + sc], &sbc[bufi][w8][0]);
  };

  stage(0, 0);
  int buf = 0;
  for (int tl = 0; tl < 32; ++tl) {
    __syncthreads();  // staged tile visible (vmcnt drained at barrier)
    if (tl + 1 < 32) stage(buf ^ 1, tl + 1);
#pragma unroll 8
    for (int t = 0; t < 32; ++t) {
      float dv = sd[buf][t][edl];
      float u = sx[buf][t][edl];
      float2 Bp = *(float2*)&sbc[buf][t][n0];
      float2 Cp = *(float2*)&sbc[buf][t][16 + n0];
      float du = dv * u;
      h0 = fmaf(__expf(dv * An0), h0, du * Bp.x);
      h1 = fmaf(__expf(dv * An1), h1, du * Bp.y);
      float py = h0 * Cp.x + h1 * Cp.y;
      py += __shfl_xor(py, 1);
      py += __shfl_xor(py, 2);
      py += __shfl_xor(py, 4);
      if (np == 0) {
        float zz = sz[buf][t][edl];
        float sig = 1.f / (1.f + __expf(-zz));
        sy[t][edl] = (py + Dv * u) * zz * sig;
      }
    }
    __syncthreads();  // sy complete
    {
      size_t row = rb + (size_t)tl * 32 + sr;
      float4 v = *(float4*)&sy[sr][sc];
      __hip_bfloat16 t4[4] = {__float2bfloat16(v.x), __float2bfloat16(v.y),
                              __float2bfloat16(v.z), __float2bfloat16(v.w)};
      *(ushort4*)&y[row * 1024 + edbase + sc] = *(ushort4*)t4;
    }
    buf ^= 1;
  }
}

// ---------------------------------------------------------------- head
__global__ __launch_bounds__(256) void head_kernel(
    const float* __restrict__ h, const float* __restrict__ hw,
    const float* __restrict__ hb, float* __restrict__ out) {
  int hc = blockIdx.x * 256 + threadIdx.x;
  int b = blockIdx.y;
  __shared__ float hs[D_];
  for (int d = threadIdx.x; d < D_; d += 256)
    hs[d] = h[((size_t)(b << 10) + 1023) * D_ + d];
  __syncthreads();
  float s = hb[hc];
#pragma unroll 8
  for (int d = 0; d < D_; ++d) s = fmaf(hs[d], hw[(size_t)hc * D_ + d], s);
  int t = hc >> 5, c = hc & 31;
  out[(size_t)b * 3072 + c * 96 + t] = s;
}

// ---------------------------------------------------------------- launch
extern "C" void kernel_launch(void* const* d_in, const int* in_sizes, int n_in,
                              void* d_out, int out_size, void* d_ws,
                              size_t ws_size, hipStream_t stream) {
  const float* x = (const float*)d_in[0];
  const float* embed_w = (const float*)d_in[1];
  const float* embed_b = (const float*)d_in[2];
  const float* norm_w = (const float*)d_in[3];
  const float* in_proj_w = (const float*)d_in[4];
  const float* conv_w = (const float*)d_in[5];
  const float* conv_b = (const float*)d_in[6];
  const float* x_proj_w = (const float*)d_in[7];
  const float* dt_proj_w = (const float*)d_in[8];
  const float* dt_proj_b = (const float*)d_in[9];
  const float* A_log = (const float*)d_in[10];
  const float* Dp = (const float*)d_in[11];
  const float* out_proj_w = (const float*)d_in[12];
  const float* head_w = (const float*)d_in[13];
  const float* head_b = (const float*)d_in[14];
  float* out = (float*)d_out;

  // ws layout: h f32 (33.5MB) | wbi bf16 (8.4MB) | wbo bf16 (4.2MB) | chunk
  // chunk/row: hn 1KB + xcr 4KB + zb 4KB + xcs 4KB + dbc 256B + ybf 2KB
  const size_t fixed = 33554432ull + 8388608ull + 4194304ull;
  const size_t rowb = 15616;
  int cb = 16;
  while (cb > 1 && fixed + (size_t)cb * 1024 * rowb > ws_size) cb >>= 1;
  if (fixed + (size_t)cb * 1024 * rowb > ws_size) return;
  const int Mc = cb * 1024;
  const int nchunks = 16 / cb;

  float* h = (float*)d_ws;
  __hip_bfloat16* wbi = (__hip_bfloat16*)((char*)d_ws + 33554432ull);
  __hip_bfloat16* wbo = wbi + 4194304;
  __hip_bfloat16* hn = wbo + 2097152;
  float* xcr = (float*)(hn + (size_t)Mc * 512);
  float* zb = xcr + (size_t)Mc * 1024;
  float* xcs = zb + (size_t)Mc * 1024;
  float* dbc = xcs + (size_t)Mc * 1024;
  __hip_bfloat16* ybf = (__hip_bfloat16*)(dbc + (size_t)Mc * 64);

  cvt_bf16_kernel<<<4096, 256, 0, stream>>>(in_proj_w, wbi, 1048576);
  cvt_bf16_kernel<<<2048, 256, 0, stream>>>(out_proj_w, wbo, 524288);
  embed_kernel<<<BL_, 256, 0, stream>>>(x, embed_w, embed_b, h);

  for (int i = 0; i < 4; ++i) {
    for (int ch = 0; ch < nchunks; ++ch) {
      float* hc = h + (size_t)ch * Mc * D_;
      rmsnorm_kernel<<<Mc, 256, 0, stream>>>(hc, norm_w + i * D_, hn);
      // xc_raw = hn @ in_w[0:1024]^T ; z = hn @ in_w[1024:2048]^T (bf16 MFMA)
      gemm_mfma_kernel<0><<<dim3(8, Mc / 128), 256, 0, stream>>>(
          hn, D_, wbi + (size_t)i * 1048576, xcr, ED_, D_);
      gemm_mfma_kernel<0><<<dim3(8, Mc / 128), 256, 0, stream>>>(
          hn, D_, wbi + (size_t)i * 1048576 + 524288, zb, ED_, D_);
      conv_silu_kernel<<<(Mc * ED_) / 256, 256, 0, stream>>>(
          xcr, conv_w + i * ED_ * DC_, conv_b + i * ED_, xcs);
      gemm_kernel<16, 0><<<dim3(4, Mc / 128), 256, 0, stream>>>(
          xcs, ED_, x_proj_w + (size_t)i * 64 * ED_, dbc, 64, nullptr, Mc, 64,
          ED_);
      gemm_kernel<128, 2><<<dim3(8, Mc / 128), 256, 0, stream>>>(
          dbc, 64, dt_proj_w + (size_t)i * ED_ * DR_, xcr, ED_,
          dt_proj_b + i * ED_, Mc, ED_, DR_);
      scan2_kernel<<<cb * 32, 256, 0, stream>>>(
          xcr, dbc, xcs, zb, A_log + (size_t)i * ED_ * N_, Dp + i * ED_, ybf);
      // h += y @ out_proj^T (bf16 MFMA, EPI=1)
      gemm_mfma_kernel<1><<<dim3(4, Mc / 128), 256, 0, stream>>>(
          ybf, ED_, wbo + (size_t)i * 524288, hc, D_, ED_);
    }
  }

  head_kernel<<<dim3(12, B_), 256, 0, stream>>>(h, head_w, head_b, out);
}

// Round 4
// 3394.926 us; speedup vs baseline: 3.3204x; 1.2911x over previous
//
#include <hip/hip_runtime.h>
#include <hip/hip_bf16.h>

// MultiVForecaster: 4-layer Mamba (B=16, L=1024, D=512, ED=1024, N=16).
// Round 4: all GEMMs via bf16 MFMA; scan with reduction hoisted out of the
// serial dependence chain (register-batched partials).

#define B_ 16
#define L_ 1024
#define D_ 512
#define ED_ 1024
#define N_ 16
#define DR_ 32
#define DC_ 4
#define BL_ (B_ * L_)

typedef __attribute__((ext_vector_type(8))) __bf16 bf16x8;
typedef __attribute__((ext_vector_type(4))) float f32x4;

#define ASYNC_LDS16(G, L)                                                      \
  __builtin_amdgcn_global_load_lds(                                            \
      (const __attribute__((address_space(1))) void*)(G),                      \
      (__attribute__((address_space(3))) void*)(L), 16, 0, 0)

// ---------------------------------------------------------------- embed
__global__ __launch_bounds__(256) void embed_kernel(
    const float* __restrict__ x, const float* __restrict__ w,
    const float* __restrict__ bias, float* __restrict__ h) {
  int bl = blockIdx.x;
  int b = bl >> 10, l = bl & 1023;
  __shared__ float xs[32];
  if (threadIdx.x < 32) xs[threadIdx.x] = x[(b * 32 + threadIdx.x) * 1024 + l];
  __syncthreads();
  for (int d = threadIdx.x; d < D_; d += 256) {
    float s = bias[d];
#pragma unroll
    for (int i = 0; i < 32; ++i) s = fmaf(xs[i], w[d * 32 + i], s);
    h[(size_t)bl * D_ + d] = s;
  }
}

// ---------------------------------------------------------------- cvt f32->bf16
__global__ __launch_bounds__(256) void cvt_bf16_kernel(
    const float* __restrict__ src, __hip_bfloat16* __restrict__ dst, int n4) {
  int i = blockIdx.x * 256 + threadIdx.x;
  if (i < n4) {
    float4 v = *(const float4*)&src[(size_t)i * 4];
    __hip_bfloat16 t4[4] = {__float2bfloat16(v.x), __float2bfloat16(v.y),
                            __float2bfloat16(v.z), __float2bfloat16(v.w)};
    *(ushort4*)&dst[(size_t)i * 4] = *(ushort4*)t4;
  }
}

// ---------------------------------------------------------------- rmsnorm -> bf16
__global__ __launch_bounds__(256) void rmsnorm_kernel(
    const float* __restrict__ h, const float* __restrict__ w,
    __hip_bfloat16* __restrict__ hn) {
  int row = blockIdx.x;
  const float* p = h + (size_t)row * D_;
  float v0 = p[threadIdx.x], v1 = p[threadIdx.x + 256];
  float ss = v0 * v0 + v1 * v1;
#pragma unroll
  for (int o = 32; o; o >>= 1) ss += __shfl_down(ss, o);
  __shared__ float red[4];
  if ((threadIdx.x & 63) == 0) red[threadIdx.x >> 6] = ss;
  __syncthreads();
  float tot = red[0] + red[1] + red[2] + red[3];
  float scale = rsqrtf(tot * (1.f / D_) + 1e-5f);
  hn[(size_t)row * D_ + threadIdx.x] =
      __float2bfloat16(v0 * scale * w[threadIdx.x]);
  hn[(size_t)row * D_ + threadIdx.x + 256] =
      __float2bfloat16(v1 * scale * w[threadIdx.x + 256]);
}

// ---------------------------------------------------------------- MFMA GEMM
// C[m,n] = sum_k A[m,k]*W[n,k]; A,W bf16 row-major K-contiguous.
// 4 waves arranged 2x2; wave tile (BM/2)x(BN/2); frags 16x16x32, BK=32.
// LDS fragment-ordered: frag f = 512 bf16 at f*512, lane l holds bytes
// [l*16, l*16+16) => ds_read_b128 conflict-free, global_load_lds dest linear.
// EPI: 0 f32 store | 1 f32 += | 2 softplus(v+bias[n]) f32 | 3 f32 + bf16 aux
//      for n<32 | 5 split: n<1024 -> f32 C, else bf16 aux (n-1024)
template <int BM, int BN, int EPI>
__global__ __launch_bounds__(256) void gemm_mfma_kernel(
    const __hip_bfloat16* __restrict__ A, int lda,
    const __hip_bfloat16* __restrict__ W, float* __restrict__ C, int ldc,
    __hip_bfloat16* __restrict__ auxb, const float* __restrict__ bias, int K) {
  constexpr int FM = BM / 32, FN = BN / 32;
  __shared__ __bf16 As[2][BM * 32];
  __shared__ __bf16 Bs[2][BN * 32];
  const int tid = threadIdx.x;
  const int w = tid >> 6, l = tid & 63;
  const int m0 = blockIdx.y * BM, n0 = blockIdx.x * BN;
  const int wr = w >> 1, wc = w & 1;
  const int lrow = l & 15, lk = (l >> 4) * 8;

  const size_t arow0 = (size_t)(m0 + w * 16 + lrow) * lda + lk;
  const size_t arow1 = (size_t)(m0 + (w + 4) * 16 + lrow) * lda + lk;
  const size_t brow0 = (size_t)(n0 + w * 16 + lrow) * K + lk;
  const size_t brow1 = (size_t)(n0 + (w + 4) * 16 + lrow) * K + lk;

  f32x4 acc[FM][FN];
#pragma unroll
  for (int i = 0; i < FM; ++i)
#pragma unroll
    for (int j = 0; j < FN; ++j) acc[i][j] = (f32x4)0.f;

  auto stage = [&](int bufi, int k0) {
    ASYNC_LDS16(A + arow0 + k0, &As[bufi][w * 512]);
    if constexpr (BM == 128) ASYNC_LDS16(A + arow1 + k0, &As[bufi][(w + 4) * 512]);
    ASYNC_LDS16(W + brow0 + k0, &Bs[bufi][w * 512]);
    if constexpr (BN == 128) ASYNC_LDS16(W + brow1 + k0, &Bs[bufi][(w + 4) * 512]);
  };

  stage(0, 0);
  int buf = 0;
  for (int k0 = 0; k0 < K; k0 += 32) {
    __syncthreads();
    if (k0 + 32 < K) stage(buf ^ 1, k0 + 32);
    bf16x8 af[FM], bfr[FN];
#pragma unroll
    for (int mi = 0; mi < FM; ++mi)
      af[mi] = *(bf16x8*)&As[buf][(wr * FM + mi) * 512 + l * 8];
#pragma unroll
    for (int ni = 0; ni < FN; ++ni)
      bfr[ni] = *(bf16x8*)&Bs[buf][(wc * FN + ni) * 512 + l * 8];
#pragma unroll
    for (int mi = 0; mi < FM; ++mi)
#pragma unroll
      for (int ni = 0; ni < FN; ++ni)
        acc[mi][ni] = __builtin_amdgcn_mfma_f32_16x16x32_bf16(
            af[mi], bfr[ni], acc[mi][ni], 0, 0, 0);
    buf ^= 1;
  }

#pragma unroll
  for (int mi = 0; mi < FM; ++mi) {
#pragma unroll
    for (int ni = 0; ni < FN; ++ni) {
      int row0 = m0 + (wr * FM + mi) * 16 + (l >> 4) * 4;
      int col = n0 + (wc * FN + ni) * 16 + (l & 15);
#pragma unroll
      for (int r = 0; r < 4; ++r) {
        int row = row0 + r;
        float v = acc[mi][ni][r];
        if (EPI == 0) {
          C[(size_t)row * ldc + col] = v;
        } else if (EPI == 1) {
          C[(size_t)row * ldc + col] += v;
        } else if (EPI == 2) {
          v += bias[col];
          v = (v > 20.f) ? v : log1pf(__expf(v));
          C[(size_t)row * ldc + col] = v;
        } else if (EPI == 3) {
          C[(size_t)row * ldc + col] = v;
          if (col < 32) auxb[(size_t)row * 32 + col] = __float2bfloat16(v);
        } else if (EPI == 5) {
          if (col < 1024)
            C[(size_t)row * 1024 + col] = v;
          else
            auxb[(size_t)row * 1024 + (col - 1024)] = __float2bfloat16(v);
        }
      }
    }
  }
}

// ---------------------------------------------------------------- conv+silu
// out f32 + bf16 copy (x_proj A-operand)
__global__ __launch_bounds__(256) void conv_silu_kernel(
    const float* __restrict__ xcr, const float* __restrict__ cw,
    const float* __restrict__ cb, float* __restrict__ out,
    __hip_bfloat16* __restrict__ outb) {
  int idx = blockIdx.x * 256 + threadIdx.x;
  int ed = idx & 1023;
  int bl = idx >> 10;
  int l = bl & 1023;
  float s = cb[ed];
#pragma unroll
  for (int j = 0; j < DC_; ++j) {
    int ll = l - 3 + j;
    if (ll >= 0)
      s = fmaf(xcr[(size_t)(bl - 3 + j) * 1024 + ed], cw[ed * 4 + j], s);
  }
  float v = s / (1.f + __expf(-s));
  out[idx] = v;
  outb[idx] = __float2bfloat16(v);
}

// ---------------------------------------------------------------- SSM scan v3
// Block = (b, 32-ed group); thread owns (ed, n-pair). Serial chain is pure
// VALU (exp+fma); n-reduction + gating batched per 32-step tile.
__global__ __launch_bounds__(256) void scan3_kernel(
    const float* __restrict__ dlt, const float* __restrict__ dbc,
    const float* __restrict__ xc, const __hip_bfloat16* __restrict__ zg,
    const float* __restrict__ A_log, const float* __restrict__ Dp,
    __hip_bfloat16* __restrict__ y) {
  const int tid = threadIdx.x;
  const int edl = tid >> 3, np = tid & 7, n0 = np * 2;
  const int b = blockIdx.x >> 5, edg = blockIdx.x & 31;
  const int edbase = edg * 32, ed = edbase + edl;
  __shared__ float sd[2][32][32], sx[2][32][32], sbc[2][32][32];
  __shared__ float sy[32][32];
  const float An0 = -__expf(A_log[ed * 16 + n0]);
  const float An1 = -__expf(A_log[ed * 16 + n0 + 1]);
  const float Dv8 = Dp[ed] * 0.125f;
  float h0 = 0.f, h1 = 0.f;
  const int sr = tid >> 3, sc = (tid & 7) * 4;  // staging row / col4
  const int w8 = (tid >> 6) * 8;                // wave's 8-row LDS base
  const size_t rb = (size_t)b * 1024;

  auto stage = [&](int bufi, int tl) {
    size_t row = rb + (size_t)tl * 32 + sr;
    ASYNC_LDS16(&dlt[row * 1024 + edbase + sc], &sd[bufi][w8][0]);
    ASYNC_LDS16(&xc[row * 1024 + edbase + sc], &sx[bufi][w8][0]);
    ASYNC_LDS16(&dbc[row * 64 + 32 + sc], &sbc[bufi][w8][0]);
  };

  stage(0, 0);
  int buf = 0;
  for (int tl = 0; tl < 32; ++tl) {
    __syncthreads();  // staged tile visible (vmcnt drained at barrier)
    if (tl + 1 < 32) stage(buf ^ 1, tl + 1);
    float preg[32];
    // ---- serial phase: no cross-lane ops in the dependence chain
#pragma unroll
    for (int t = 0; t < 32; ++t) {
      float dv = sd[buf][t][edl];
      float u = sx[buf][t][edl];
      float2 Bp = *(float2*)&sbc[buf][t][n0];
      float2 Cp = *(float2*)&sbc[buf][t][16 + n0];
      float du = dv * u;
      h0 = fmaf(__expf(dv * An0), h0, du * Bp.x);
      h1 = fmaf(__expf(dv * An1), h1, du * Bp.y);
      preg[t] = fmaf(Dv8, u, fmaf(h0, Cp.x, h1 * Cp.y));
    }
    // ---- reduce phase: 32 independent 8-lane reductions
#pragma unroll
    for (int t = 0; t < 32; ++t) {
      float v = preg[t];
      v += __shfl_xor(v, 1);
      v += __shfl_xor(v, 2);
      v += __shfl_xor(v, 4);
      if (np == 0) sy[t][edl] = v;
    }
    __syncthreads();  // sy complete
    // ---- store phase: gate with silu(z), emit bf16
    {
      size_t row = rb + (size_t)tl * 32 + sr;
      float4 v = *(float4*)&sy[sr][sc];
      ushort4 zv = *(const ushort4*)&zg[row * 1024 + edbase + sc];
      float vo[4] = {v.x, v.y, v.z, v.w};
      unsigned short zo[4] = {zv.x, zv.y, zv.z, zv.w};
      __hip_bfloat16 t4[4];
#pragma unroll
      for (int j = 0; j < 4; ++j) {
        float zz = __bfloat162float(*(__hip_bfloat16*)&zo[j]);
        float g = zz / (1.f + __expf(-zz));
        t4[j] = __float2bfloat16(vo[j] * g);
      }
      *(ushort4*)&y[row * 1024 + edbase + sc] = *(ushort4*)t4;
    }
    buf ^= 1;
  }
}

// ---------------------------------------------------------------- head
__global__ __launch_bounds__(256) void head_kernel(
    const float* __restrict__ h, const float* __restrict__ hw,
    const float* __restrict__ hb, float* __restrict__ out) {
  int hc = blockIdx.x * 256 + threadIdx.x;
  int b = blockIdx.y;
  __shared__ float hs[D_];
  for (int d = threadIdx.x; d < D_; d += 256)
    hs[d] = h[((size_t)(b << 10) + 1023) * D_ + d];
  __syncthreads();
  float s = hb[hc];
#pragma unroll 8
  for (int d = 0; d < D_; ++d) s = fmaf(hs[d], hw[(size_t)hc * D_ + d], s);
  int t = hc >> 5, c = hc & 31;
  out[(size_t)b * 3072 + c * 96 + t] = s;
}

// ---------------------------------------------------------------- launch
extern "C" void kernel_launch(void* const* d_in, const int* in_sizes, int n_in,
                              void* d_out, int out_size, void* d_ws,
                              size_t ws_size, hipStream_t stream) {
  const float* x = (const float*)d_in[0];
  const float* embed_w = (const float*)d_in[1];
  const float* embed_b = (const float*)d_in[2];
  const float* norm_w = (const float*)d_in[3];
  const float* in_proj_w = (const float*)d_in[4];
  const float* conv_w = (const float*)d_in[5];
  const float* conv_b = (const float*)d_in[6];
  const float* x_proj_w = (const float*)d_in[7];
  const float* dt_proj_w = (const float*)d_in[8];
  const float* dt_proj_b = (const float*)d_in[9];
  const float* A_log = (const float*)d_in[10];
  const float* Dp = (const float*)d_in[11];
  const float* out_proj_w = (const float*)d_in[12];
  const float* head_w = (const float*)d_in[13];
  const float* head_b = (const float*)d_in[14];
  float* out = (float*)d_out;

  // fixed: h f32 33.5MB | wbi 8.4MB | wbo 4.2MB | wxp 0.5MB | wdt 0.25MB
  // chunk/row: hn 1024B + xcs_bf 2048 + xcr 4096 + zb 2048 + xcs 4096 +
  //            dbc 256 + dbc_bf 64 = 13632 B.  ybf aliases hn+xcs_bf.
  const size_t fixed = 33554432ull + 8388608ull + 4194304ull + 524288ull +
                       262144ull;
  const size_t rowb = 13632;
  int cb = 16;
  while (cb > 1 && fixed + (size_t)cb * 1024 * rowb > ws_size) cb >>= 1;
  if (fixed + (size_t)cb * 1024 * rowb > ws_size) return;
  const int Mc = cb * 1024;
  const int nchunks = 16 / cb;

  char* p = (char*)d_ws;
  float* h = (float*)p;                 p += 33554432ull;
  __hip_bfloat16* wbi = (__hip_bfloat16*)p; p += 8388608ull;
  __hip_bfloat16* wbo = (__hip_bfloat16*)p; p += 4194304ull;
  __hip_bfloat16* wxp = (__hip_bfloat16*)p; p += 524288ull;
  __hip_bfloat16* wdt = (__hip_bfloat16*)p; p += 262144ull;
  __hip_bfloat16* hn = (__hip_bfloat16*)p;  p += (size_t)Mc * 1024;
  __hip_bfloat16* xcs_bf = (__hip_bfloat16*)p; p += (size_t)Mc * 2048;
  float* xcr = (float*)p;               p += (size_t)Mc * 4096;
  __hip_bfloat16* zb = (__hip_bfloat16*)p;  p += (size_t)Mc * 2048;
  float* xcs = (float*)p;               p += (size_t)Mc * 4096;
  float* dbc = (float*)p;               p += (size_t)Mc * 256;
  __hip_bfloat16* dbc_bf = (__hip_bfloat16*)p;
  __hip_bfloat16* ybf = hn;  // alias over dead hn + xcs_bf (3KB/row >= 2KB)

  cvt_bf16_kernel<<<4096, 256, 0, stream>>>(in_proj_w, wbi, 1048576);
  cvt_bf16_kernel<<<2048, 256, 0, stream>>>(out_proj_w, wbo, 524288);
  cvt_bf16_kernel<<<256, 256, 0, stream>>>(x_proj_w, wxp, 65536);
  cvt_bf16_kernel<<<128, 256, 0, stream>>>(dt_proj_w, wdt, 32768);
  embed_kernel<<<BL_, 256, 0, stream>>>(x, embed_w, embed_b, h);

  for (int i = 0; i < 4; ++i) {
    for (int ch = 0; ch < nchunks; ++ch) {
      float* hc = h + (size_t)ch * Mc * D_;
      rmsnorm_kernel<<<Mc, 256, 0, stream>>>(hc, norm_w + i * D_, hn);
      // fused in_proj: cols<1024 -> xcr f32, cols>=1024 -> zb bf16
      gemm_mfma_kernel<128, 128, 5><<<dim3(16, Mc / 128), 256, 0, stream>>>(
          hn, D_, wbi + (size_t)i * 1048576, xcr, 0, zb, nullptr, D_);
      conv_silu_kernel<<<(Mc * ED_) / 256, 256, 0, stream>>>(
          xcr, conv_w + i * ED_ * DC_, conv_b + i * ED_, xcs, xcs_bf);
      // x_proj: dbc f32 (64) + dbc_bf bf16 (cols<32)
      gemm_mfma_kernel<64, 64, 3><<<dim3(1, Mc / 64), 256, 0, stream>>>(
          xcs_bf, ED_, wxp + (size_t)i * 65536, dbc, 64, dbc_bf, nullptr, ED_);
      // dt_proj: delta = softplus(dbc_bf @ wdt^T + b) -> xcr
      gemm_mfma_kernel<128, 128, 2><<<dim3(8, Mc / 128), 256, 0, stream>>>(
          dbc_bf, DR_, wdt + (size_t)i * 32768, xcr, ED_, nullptr,
          dt_proj_b + i * ED_, DR_);
      scan3_kernel<<<cb * 32, 256, 0, stream>>>(
          xcr, dbc, xcs, zb, A_log + (size_t)i * ED_ * N_, Dp + i * ED_, ybf);
      // h += y @ out_proj^T
      gemm_mfma_kernel<128, 128, 1><<<dim3(4, Mc / 128), 256, 0, stream>>>(
          ybf, ED_, wbo + (size_t)i * 524288, hc, D_, nullptr, nullptr, ED_);
    }
  }

  head_kernel<<<dim3(12, B_), 256, 0, stream>>>(h, head_w, head_b, out);
}

// Round 5
// 2932.420 us; speedup vs baseline: 3.8441x; 1.1577x over previous
//
#include <hip/hip_runtime.h>
#include <hip/hip_bf16.h>

// MultiVForecaster: 4-layer Mamba (B=16, L=1024, D=512, ED=1024, N=16).
// Round 5: chunked-parallel SSM scan (3 phases, exact reassociation),
// bf16 activation flow, XCD-swizzled MFMA GEMMs.

#define B_ 16
#define L_ 1024
#define D_ 512
#define ED_ 1024
#define N_ 16
#define DR_ 32
#define DC_ 4
#define BL_ (B_ * L_)

typedef __attribute__((ext_vector_type(8))) __bf16 bf16x8;
typedef __attribute__((ext_vector_type(4))) float f32x4;

#define ASYNC_LDS16(G, L)                                                      \
  __builtin_amdgcn_global_load_lds(                                            \
      (const __attribute__((address_space(1))) void*)(G),                      \
      (__attribute__((address_space(3))) void*)(L), 16, 0, 0)

// ---------------------------------------------------------------- embed
__global__ __launch_bounds__(256) void embed_kernel(
    const float* __restrict__ x, const float* __restrict__ w,
    const float* __restrict__ bias, float* __restrict__ h) {
  int bl = blockIdx.x;
  int b = bl >> 10, l = bl & 1023;
  __shared__ float xs[32];
  if (threadIdx.x < 32) xs[threadIdx.x] = x[(b * 32 + threadIdx.x) * 1024 + l];
  __syncthreads();
  for (int d = threadIdx.x; d < D_; d += 256) {
    float s = bias[d];
#pragma unroll
    for (int i = 0; i < 32; ++i) s = fmaf(xs[i], w[d * 32 + i], s);
    h[(size_t)bl * D_ + d] = s;
  }
}

// ---------------------------------------------------------------- cvt f32->bf16
__global__ __launch_bounds__(256) void cvt_bf16_kernel(
    const float* __restrict__ src, __hip_bfloat16* __restrict__ dst, int n4) {
  int i = blockIdx.x * 256 + threadIdx.x;
  if (i < n4) {
    float4 v = *(const float4*)&src[(size_t)i * 4];
    __hip_bfloat16 t4[4] = {__float2bfloat16(v.x), __float2bfloat16(v.y),
                            __float2bfloat16(v.z), __float2bfloat16(v.w)};
    *(ushort4*)&dst[(size_t)i * 4] = *(ushort4*)t4;
  }
}

// ---------------------------------------------------------------- rmsnorm -> bf16
__global__ __launch_bounds__(256) void rmsnorm_kernel(
    const float* __restrict__ h, const float* __restrict__ w,
    __hip_bfloat16* __restrict__ hn) {
  int row = blockIdx.x;
  const float* p = h + (size_t)row * D_;
  float v0 = p[threadIdx.x], v1 = p[threadIdx.x + 256];
  float ss = v0 * v0 + v1 * v1;
#pragma unroll
  for (int o = 32; o; o >>= 1) ss += __shfl_down(ss, o);
  __shared__ float red[4];
  if ((threadIdx.x & 63) == 0) red[threadIdx.x >> 6] = ss;
  __syncthreads();
  float tot = red[0] + red[1] + red[2] + red[3];
  float scale = rsqrtf(tot * (1.f / D_) + 1e-5f);
  hn[(size_t)row * D_ + threadIdx.x] =
      __float2bfloat16(v0 * scale * w[threadIdx.x]);
  hn[(size_t)row * D_ + threadIdx.x + 256] =
      __float2bfloat16(v1 * scale * w[threadIdx.x + 256]);
}

// ---------------------------------------------------------------- MFMA GEMM
// C[m,n] = sum_k A[m,k]*W[n,k]; A,W bf16 row-major K-contiguous.
// 4 waves 2x2; frags 16x16x32, BK=32; LDS fragment-ordered (conflict-free).
// Bijective XCD swizzle on linearized block id (m204): consecutive logical
// tiles (sharing an A panel) land on the same XCD's L2.
// EPI: 0 f32 store | 1 f32 += | 2 softplus(v+bias[n]) f32 |
//      3 f32 + bf16 aux (n<32) | 5 bf16 split: n<1024->auxb, else auxb2
template <int BM, int BN, int EPI>
__global__ __launch_bounds__(256) void gemm_mfma_kernel(
    const __hip_bfloat16* __restrict__ A, int lda,
    const __hip_bfloat16* __restrict__ W, float* __restrict__ C, int ldc,
    __hip_bfloat16* __restrict__ auxb, __hip_bfloat16* __restrict__ auxb2,
    const float* __restrict__ bias, int K) {
  constexpr int FM = BM / 32, FN = BN / 32;
  __shared__ __bf16 As[2][BM * 32];
  __shared__ __bf16 Bs[2][BN * 32];
  const int tid = threadIdx.x;
  const int w = tid >> 6, l = tid & 63;
  // XCD-aware bijective swizzle
  const int gx = gridDim.x;
  const int nwg = gx * gridDim.y;
  const int wg = blockIdx.y * gx + blockIdx.x;
  const int q = nwg >> 3, r = nwg & 7;
  const int xcd = wg & 7, pos = wg >> 3;
  const int wgid =
      (xcd < r ? xcd * (q + 1) : r * (q + 1) + (xcd - r) * q) + pos;
  const int m0 = (wgid / gx) * BM, n0 = (wgid % gx) * BN;
  const int wr = w >> 1, wc = w & 1;
  const int lrow = l & 15, lk = (l >> 4) * 8;

  const size_t arow0 = (size_t)(m0 + w * 16 + lrow) * lda + lk;
  const size_t arow1 = (size_t)(m0 + (w + 4) * 16 + lrow) * lda + lk;
  const size_t brow0 = (size_t)(n0 + w * 16 + lrow) * K + lk;
  const size_t brow1 = (size_t)(n0 + (w + 4) * 16 + lrow) * K + lk;

  f32x4 acc[FM][FN];
#pragma unroll
  for (int i = 0; i < FM; ++i)
#pragma unroll
    for (int j = 0; j < FN; ++j) acc[i][j] = (f32x4)0.f;

  auto stage = [&](int bufi, int k0) {
    ASYNC_LDS16(A + arow0 + k0, &As[bufi][w * 512]);
    if constexpr (BM == 128)
      ASYNC_LDS16(A + arow1 + k0, &As[bufi][(w + 4) * 512]);
    ASYNC_LDS16(W + brow0 + k0, &Bs[bufi][w * 512]);
    if constexpr (BN == 128)
      ASYNC_LDS16(W + brow1 + k0, &Bs[bufi][(w + 4) * 512]);
  };

  stage(0, 0);
  int buf = 0;
  for (int k0 = 0; k0 < K; k0 += 32) {
    __syncthreads();
    if (k0 + 32 < K) stage(buf ^ 1, k0 + 32);
    bf16x8 af[FM], bfr[FN];
#pragma unroll
    for (int mi = 0; mi < FM; ++mi)
      af[mi] = *(bf16x8*)&As[buf][(wr * FM + mi) * 512 + l * 8];
#pragma unroll
    for (int ni = 0; ni < FN; ++ni)
      bfr[ni] = *(bf16x8*)&Bs[buf][(wc * FN + ni) * 512 + l * 8];
#pragma unroll
    for (int mi = 0; mi < FM; ++mi)
#pragma unroll
      for (int ni = 0; ni < FN; ++ni)
        acc[mi][ni] = __builtin_amdgcn_mfma_f32_16x16x32_bf16(
            af[mi], bfr[ni], acc[mi][ni], 0, 0, 0);
    buf ^= 1;
  }

#pragma unroll
  for (int mi = 0; mi < FM; ++mi) {
#pragma unroll
    for (int ni = 0; ni < FN; ++ni) {
      int row0 = m0 + (wr * FM + mi) * 16 + (l >> 4) * 4;
      int col = n0 + (wc * FN + ni) * 16 + (l & 15);
#pragma unroll
      for (int r2 = 0; r2 < 4; ++r2) {
        int row = row0 + r2;
        float v = acc[mi][ni][r2];
        if (EPI == 0) {
          C[(size_t)row * ldc + col] = v;
        } else if (EPI == 1) {
          C[(size_t)row * ldc + col] += v;
        } else if (EPI == 2) {
          v += bias[col];
          v = (v > 20.f) ? v : log1pf(__expf(v));
          C[(size_t)row * ldc + col] = v;
        } else if (EPI == 3) {
          C[(size_t)row * ldc + col] = v;
          if (col < 32) auxb[(size_t)row * 32 + col] = __float2bfloat16(v);
        } else if (EPI == 5) {
          if (col < 1024)
            auxb[(size_t)row * 1024 + col] = __float2bfloat16(v);
          else
            auxb2[(size_t)row * 1024 + (col - 1024)] = __float2bfloat16(v);
        }
      }
    }
  }
}

// ---------------------------------------------------------------- conv+silu
// bf16 in (raw xc), bf16 out (u = silu(conv)); causal within each batch.
__global__ __launch_bounds__(256) void conv_silu_kernel(
    const __hip_bfloat16* __restrict__ xcb, const float* __restrict__ cw,
    const float* __restrict__ cb, __hip_bfloat16* __restrict__ out) {
  int idx = blockIdx.x * 256 + threadIdx.x;
  int ed = idx & 1023;
  int bl = idx >> 10;
  int l = bl & 1023;
  float s = cb[ed];
#pragma unroll
  for (int j = 0; j < DC_; ++j) {
    int ll = l - 3 + j;
    if (ll >= 0)
      s = fmaf(__bfloat162float(xcb[(size_t)(bl - 3 + j) * 1024 + ed]),
               cw[ed * 4 + j], s);
  }
  float v = s / (1.f + __expf(-s));
  out[idx] = __float2bfloat16(v);
}

// ---------------------------------------------------------------- scan phase 1
// Local scan per (b, chunk of 64 steps, 32-ed group), h starts at 0.
// Whole chunk staged up-front (no mid-loop staging). Outputs: y_local f32,
// inclusive cumdelta f32, chunk-final states S, chunk total delta.
__global__ __launch_bounds__(256) void scan_p1_kernel(
    const float* __restrict__ dlt, const float* __restrict__ dbc,
    const __hip_bfloat16* __restrict__ xcb, const float* __restrict__ A_log,
    const float* __restrict__ Dp, float* __restrict__ yl,
    float* __restrict__ scd, float* __restrict__ S, float* __restrict__ totd) {
  const int tid = threadIdx.x;
  const int edl = tid >> 3, np = tid & 7, n0 = np * 2;
  const int g = blockIdx.x & 31;
  const int c = (blockIdx.x >> 5) & 15;
  const int b = blockIdx.x >> 9;
  const int edbase = g * 32, ed = edbase + edl;
  __shared__ float sd[64][32];
  __shared__ float sbc[64][32];
  __shared__ __hip_bfloat16 su[64][32];
  __shared__ float sy[32][32], s2[32][32];
  const float An0 = -__expf(A_log[ed * 16 + n0]);
  const float An1 = -__expf(A_log[ed * 16 + n0 + 1]);
  const float Dv8 = Dp[ed] * 0.125f;
  const int w = tid >> 6;
  const int sr = tid >> 3, sc = (tid & 7) * 4;   // f32 staging: 8 lanes/row
  const int ur = tid >> 2, uc = (tid & 3) * 8;   // bf16 staging: 4 lanes/row
  const size_t row0 = (size_t)b * 1024 + c * 64;

  ASYNC_LDS16(&dlt[(row0 + sr) * 1024 + edbase + sc], &sd[w * 8][0]);
  ASYNC_LDS16(&dlt[(row0 + 32 + sr) * 1024 + edbase + sc], &sd[32 + w * 8][0]);
  ASYNC_LDS16(&dbc[(row0 + sr) * 64 + 32 + sc], &sbc[w * 8][0]);
  ASYNC_LDS16(&dbc[(row0 + 32 + sr) * 64 + 32 + sc], &sbc[32 + w * 8][0]);
  ASYNC_LDS16(&xcb[(row0 + ur) * 1024 + edbase + uc], &su[w * 16][0]);

  float h0 = 0.f, h1 = 0.f, cd = 0.f;
  __syncthreads();
#pragma unroll
  for (int tl = 0; tl < 2; ++tl) {
    float preg[32];
#pragma unroll
    for (int t = 0; t < 32; ++t) {
      const int tt = tl * 32 + t;
      float dv = sd[tt][edl];
      float u = __bfloat162float(su[tt][edl]);
      float2 Bp = *(float2*)&sbc[tt][n0];
      float2 Cp = *(float2*)&sbc[tt][16 + n0];
      float du = dv * u;
      h0 = fmaf(__expf(dv * An0), h0, du * Bp.x);
      h1 = fmaf(__expf(dv * An1), h1, du * Bp.y);
      cd += dv;
      if (np == 0) s2[t][edl] = cd;
      preg[t] = fmaf(Dv8, u, fmaf(h0, Cp.x, h1 * Cp.y));
    }
#pragma unroll
    for (int t = 0; t < 32; ++t) {
      float v = preg[t];
      v += __shfl_xor(v, 1);
      v += __shfl_xor(v, 2);
      v += __shfl_xor(v, 4);
      if (np == 0) sy[t][edl] = v;
    }
    __syncthreads();
    {
      size_t row = row0 + tl * 32 + sr;
      *(float4*)&yl[row * 1024 + edbase + sc] = *(float4*)&sy[sr][sc];
      *(float4*)&scd[row * 1024 + edbase + sc] = *(float4*)&s2[sr][sc];
    }
    __syncthreads();
  }
  size_t sidx = (((size_t)b * 16 + c) * 1024 + ed) * 16 + n0;
  *(float2*)&S[sidx] = make_float2(h0, h1);
  if (np == 0) totd[((size_t)b * 16 + c) * 1024 + ed] = cd;
}

// ---------------------------------------------------------------- scan phase 2
// Chunk-state prefix: HP[b,c,ed,n] = H_{c-1}; H_c = exp(An*totd_c)*H + S_c.
__global__ __launch_bounds__(256) void scan_p2_kernel(
    const float* __restrict__ S, const float* __restrict__ totd,
    const float* __restrict__ A_log, float* __restrict__ HP) {
  int t = blockIdx.x * 256 + threadIdx.x;
  int n = t & 15, ed = (t >> 4) & 1023;
  int b = t >> 14;
  float An = -__expf(A_log[ed * 16 + n]);
  float H = 0.f;
#pragma unroll
  for (int c = 0; c < 16; ++c) {
    size_t i = ((size_t)b * 16 + c) * 1024 + ed;
    HP[i * 16 + n] = H;
    H = fmaf(__expf(An * totd[i]), H, S[i * 16 + n]);
  }
}

// ---------------------------------------------------------------- scan phase 3
// y = (y_local + sum_n exp(An*cumd)*C_n*Hprev_n) * silu(z), bf16 out.
__global__ __launch_bounds__(256) void scan_p3_kernel(
    const float* __restrict__ yl, const float* __restrict__ scd,
    const float* __restrict__ dbc, const __hip_bfloat16* __restrict__ zb,
    const float* __restrict__ A_log, const float* __restrict__ HP,
    __hip_bfloat16* __restrict__ y) {
  const int tid = threadIdx.x;
  const int g = blockIdx.x & 31;
  const int c = (blockIdx.x >> 5) & 15;
  const int b = blockIdx.x >> 9;
  const int ed = g * 32 + (tid & 31), rg = tid >> 5;
  __shared__ float sC[64][16];
  {
    int rr = tid >> 2, qq = (tid & 3) * 4;
    size_t row = (size_t)b * 1024 + c * 64 + rr;
    *(float4*)&sC[rr][qq] = *(const float4*)&dbc[row * 64 + 48 + qq];
  }
  float An[16], Hp[16];
#pragma unroll
  for (int n = 0; n < 16; n += 4) {
    float4 a = *(const float4*)&A_log[ed * 16 + n];
    An[n] = -__expf(a.x);
    An[n + 1] = -__expf(a.y);
    An[n + 2] = -__expf(a.z);
    An[n + 3] = -__expf(a.w);
    *(float4*)&Hp[n] =
        *(const float4*)&HP[(((size_t)b * 16 + c) * 1024 + ed) * 16 + n];
  }
  __syncthreads();
#pragma unroll
  for (int rr = 0; rr < 8; ++rr) {
    const int rl = rg * 8 + rr;
    const size_t row = (size_t)b * 1024 + c * 64 + rl;
    float acc = yl[row * 1024 + ed];
    float cds = scd[row * 1024 + ed];
#pragma unroll
    for (int n = 0; n < 16; ++n)
      acc = fmaf(__expf(An[n] * cds) * Hp[n], sC[rl][n], acc);
    float zz = __bfloat162float(zb[row * 1024 + ed]);
    acc *= zz / (1.f + __expf(-zz));
    y[row * 1024 + ed] = __float2bfloat16(acc);
  }
}

// ---------------------------------------------------------------- head
__global__ __launch_bounds__(256) void head_kernel(
    const float* __restrict__ h, const float* __restrict__ hw,
    const float* __restrict__ hb, float* __restrict__ out) {
  int hc = blockIdx.x * 256 + threadIdx.x;
  int b = blockIdx.y;
  __shared__ float hs[D_];
  for (int d = threadIdx.x; d < D_; d += 256)
    hs[d] = h[((size_t)(b << 10) + 1023) * D_ + d];
  __syncthreads();
  float s = hb[hc];
#pragma unroll 8
  for (int d = 0; d < D_; ++d) s = fmaf(hs[d], hw[(size_t)hc * D_ + d], s);
  int t = hc >> 5, c = hc & 31;
  out[(size_t)b * 3072 + c * 96 + t] = s;
}

// ---------------------------------------------------------------- launch
extern "C" void kernel_launch(void* const* d_in, const int* in_sizes, int n_in,
                              void* d_out, int out_size, void* d_ws,
                              size_t ws_size, hipStream_t stream) {
  const float* x = (const float*)d_in[0];
  const float* embed_w = (const float*)d_in[1];
  const float* embed_b = (const float*)d_in[2];
  const float* norm_w = (const float*)d_in[3];
  const float* in_proj_w = (const float*)d_in[4];
  const float* conv_w = (const float*)d_in[5];
  const float* conv_b = (const float*)d_in[6];
  const float* x_proj_w = (const float*)d_in[7];
  const float* dt_proj_w = (const float*)d_in[8];
  const float* dt_proj_b = (const float*)d_in[9];
  const float* A_log = (const float*)d_in[10];
  const float* Dp = (const float*)d_in[11];
  const float* out_proj_w = (const float*)d_in[12];
  const float* head_w = (const float*)d_in[13];
  const float* head_b = (const float*)d_in[14];
  float* out = (float*)d_out;

  // fixed: h 33.5MB | wbi 8.4 | wbo 4.2 | wxp 0.5 | wdt 0.25 | S,HP,totd(cb)
  // per row: hn 1024 | xcrbf 2048 | zb 2048 | xcsbf 2048 | dbc 256 |
  //          dbcbf 64 | dlt 4096 | yl 4096 | scd 4096  = 19776 B
  const size_t fixed0 =
      33554432ull + 8388608ull + 4194304ull + 524288ull + 262144ull;
  auto need = [&](int cbx) {
    return fixed0 + (size_t)cbx * (2ull * 1048576 + 65536) +
           (size_t)cbx * 1024 * 19776;
  };
  int cb = 16;
  while (cb > 1 && need(cb) > ws_size) cb >>= 1;
  if (need(cb) > ws_size) return;
  const int Mc = cb * 1024;
  const int nchunks = 16 / cb;

  char* p = (char*)d_ws;
  float* h = (float*)p;                        p += 33554432ull;
  __hip_bfloat16* wbi = (__hip_bfloat16*)p;    p += 8388608ull;
  __hip_bfloat16* wbo = (__hip_bfloat16*)p;    p += 4194304ull;
  __hip_bfloat16* wxp = (__hip_bfloat16*)p;    p += 524288ull;
  __hip_bfloat16* wdt = (__hip_bfloat16*)p;    p += 262144ull;
  float* S = (float*)p;                        p += (size_t)cb * 1048576;
  float* HP = (float*)p;                       p += (size_t)cb * 1048576;
  float* totd = (float*)p;                     p += (size_t)cb * 65536;
  __hip_bfloat16* hn = (__hip_bfloat16*)p;     p += (size_t)Mc * 1024;
  __hip_bfloat16* xcrbf = (__hip_bfloat16*)p;  p += (size_t)Mc * 2048;
  __hip_bfloat16* zb = (__hip_bfloat16*)p;     p += (size_t)Mc * 2048;
  __hip_bfloat16* xcsbf = (__hip_bfloat16*)p;  p += (size_t)Mc * 2048;
  float* dbc = (float*)p;                      p += (size_t)Mc * 256;
  __hip_bfloat16* dbcbf = (__hip_bfloat16*)p;  p += (size_t)Mc * 64;
  float* dlt = (float*)p;                      p += (size_t)Mc * 4096;
  float* yl = (float*)p;                       p += (size_t)Mc * 4096;
  float* scd = (float*)p;                      p += (size_t)Mc * 4096;
  // y (bf16, Mc*2048 B) aliases [hn | xcrbf] (3*Mc KB): both dead by phase 3.
  __hip_bfloat16* ybf = hn;

  cvt_bf16_kernel<<<4096, 256, 0, stream>>>(in_proj_w, wbi, 1048576);
  cvt_bf16_kernel<<<2048, 256, 0, stream>>>(out_proj_w, wbo, 524288);
  cvt_bf16_kernel<<<256, 256, 0, stream>>>(x_proj_w, wxp, 65536);
  cvt_bf16_kernel<<<128, 256, 0, stream>>>(dt_proj_w, wdt, 32768);
  embed_kernel<<<BL_, 256, 0, stream>>>(x, embed_w, embed_b, h);

  for (int i = 0; i < 4; ++i) {
    for (int ch = 0; ch < nchunks; ++ch) {
      float* hc = h + (size_t)ch * Mc * D_;
      rmsnorm_kernel<<<Mc, 256, 0, stream>>>(hc, norm_w + i * D_, hn);
      // in_proj: n<1024 -> xcrbf (bf16), n>=1024 -> zb (bf16)
      gemm_mfma_kernel<128, 128, 5><<<dim3(16, Mc / 128), 256, 0, stream>>>(
          hn, D_, wbi + (size_t)i * 1048576, nullptr, 0, xcrbf, zb, nullptr,
          D_);
      conv_silu_kernel<<<(Mc * ED_) / 256, 256, 0, stream>>>(
          xcrbf, conv_w + i * ED_ * DC_, conv_b + i * ED_, xcsbf);
      // x_proj: dbc f32 (64 cols) + dbcbf bf16 (cols<32)
      gemm_mfma_kernel<64, 64, 3><<<dim3(1, Mc / 64), 256, 0, stream>>>(
          xcsbf, ED_, wxp + (size_t)i * 65536, dbc, 64, dbcbf, nullptr,
          nullptr, ED_);
      // dt_proj: delta = softplus(dbcbf @ wdt^T + b) -> dlt f32
      gemm_mfma_kernel<128, 128, 2><<<dim3(8, Mc / 128), 256, 0, stream>>>(
          dbcbf, DR_, wdt + (size_t)i * 32768, dlt, ED_, nullptr, nullptr,
          dt_proj_b + i * ED_, DR_);
      scan_p1_kernel<<<cb * 512, 256, 0, stream>>>(
          dlt, dbc, xcsbf, A_log + (size_t)i * ED_ * N_, Dp + i * ED_, yl, scd,
          S, totd);
      scan_p2_kernel<<<cb * 64, 256, 0, stream>>>(
          S, totd, A_log + (size_t)i * ED_ * N_, HP);
      scan_p3_kernel<<<cb * 512, 256, 0, stream>>>(
          yl, scd, dbc, zb, A_log + (size_t)i * ED_ * N_, HP, ybf);
      // h += y @ out_proj^T
      gemm_mfma_kernel<128, 128, 1><<<dim3(4, Mc / 128), 256, 0, stream>>>(
          ybf, ED_, wbo + (size_t)i * 524288, hc, D_, nullptr, nullptr,
          nullptr, ED_);
    }
  }

  head_kernel<<<dim3(12, B_), 256, 0, stream>>>(h, head_w, head_b, out);
}

// Round 6
// 2603.255 us; speedup vs baseline: 4.3302x; 1.1264x over previous
//
#include <hip/hip_runtime.h>
#include <hip/hip_bf16.h>

// MultiVForecaster: 4-layer Mamba (B=16, L=1024, D=512, ED=1024, N=16).
// Round 6: fast embed, states-only p1 + rescan p3 (no yl/scd traffic),
// dt_proj folded into combined GEMM, vectorized conv/rmsnorm.

#define B_ 16
#define L_ 1024
#define D_ 512
#define ED_ 1024
#define N_ 16
#define DR_ 32
#define DC_ 4
#define BL_ (B_ * L_)

typedef __attribute__((ext_vector_type(8))) __bf16 bf16x8;
typedef __attribute__((ext_vector_type(4))) float f32x4;

#define ASYNC_LDS16(G, L)                                                      \
  __builtin_amdgcn_global_load_lds(                                            \
      (const __attribute__((address_space(1))) void*)(G),                      \
      (__attribute__((address_space(3))) void*)(L), 16, 0, 0)

// ---------------------------------------------------------------- embed
// h[b,l,d] = sum_i x[b,i,l]*w[d,i] + bias[d].  Block = (64 l) x (512 d),
// w staged to LDS [32][513] (conflict-free), then held in registers.
__global__ __launch_bounds__(256) void embed_kernel(
    const float* __restrict__ x, const float* __restrict__ w,
    const float* __restrict__ bias, float* __restrict__ h) {
  __shared__ float xs[64][36];
  __shared__ float ws[32][513];
  const int tid = threadIdx.x;
  const int b = blockIdx.y, l0 = blockIdx.x * 64;
  for (int f = tid; f < 16384; f += 256) {
    int d = f >> 5, i = f & 31;
    ws[i][d] = w[f];
  }
  for (int f = tid; f < 2048; f += 256) {
    int i = f >> 6, l = f & 63;
    xs[l][i] = x[b * 32768 + i * 1024 + l0 + l];
  }
  const int d0 = tid, d1 = tid + 256;
  __syncthreads();
  float wr0[32], wr1[32];
#pragma unroll
  for (int i = 0; i < 32; ++i) {
    wr0[i] = ws[i][d0];
    wr1[i] = ws[i][d1];
  }
  const float b0 = bias[d0], b1 = bias[d1];
  for (int l = 0; l < 64; ++l) {
    float a0 = b0, a1 = b1;
#pragma unroll
    for (int q = 0; q < 8; ++q) {
      float4 xv = *(float4*)&xs[l][q * 4];
      a0 = fmaf(xv.x, wr0[q * 4], a0);
      a1 = fmaf(xv.x, wr1[q * 4], a1);
      a0 = fmaf(xv.y, wr0[q * 4 + 1], a0);
      a1 = fmaf(xv.y, wr1[q * 4 + 1], a1);
      a0 = fmaf(xv.z, wr0[q * 4 + 2], a0);
      a1 = fmaf(xv.z, wr1[q * 4 + 2], a1);
      a0 = fmaf(xv.w, wr0[q * 4 + 3], a0);
      a1 = fmaf(xv.w, wr1[q * 4 + 3], a1);
    }
    size_t row = (size_t)(b << 10) + l0 + l;
    h[row * 512 + d0] = a0;
    h[row * 512 + d1] = a1;
  }
}

// ---------------------------------------------------------------- cvt f32->bf16
__global__ __launch_bounds__(256) void cvt_bf16_kernel(
    const float* __restrict__ src, __hip_bfloat16* __restrict__ dst, int n4) {
  int i = blockIdx.x * 256 + threadIdx.x;
  if (i < n4) {
    float4 v = *(const float4*)&src[(size_t)i * 4];
    __hip_bfloat16 t4[4] = {__float2bfloat16(v.x), __float2bfloat16(v.y),
                            __float2bfloat16(v.z), __float2bfloat16(v.w)};
    *(ushort4*)&dst[(size_t)i * 4] = *(ushort4*)t4;
  }
}

// wxpT[i][k,r] = x_proj_w[i][r,k], r<32 (dt_rank rows only)
__global__ __launch_bounds__(256) void transpose_xp_kernel(
    const float* __restrict__ xp, __hip_bfloat16* __restrict__ xpT) {
  int t = blockIdx.x * 256 + threadIdx.x;  // 131072
  int r = t & 31, k = (t >> 5) & 1023, i = t >> 15;
  xpT[i * 32768 + k * 32 + r] =
      __float2bfloat16(xp[i * 65536 + r * 1024 + k]);
}

// ---------------------------------------------------------------- rmsnorm
__global__ __launch_bounds__(256) void rmsnorm_kernel(
    const float* __restrict__ h, const float* __restrict__ w,
    __hip_bfloat16* __restrict__ hn) {
  const int tid = threadIdx.x;
  const int row = blockIdx.x * 2 + (tid >> 7);
  const int t = tid & 127;
  float4 v = *(const float4*)&h[(size_t)row * 512 + t * 4];
  float ss = v.x * v.x + v.y * v.y + v.z * v.z + v.w * v.w;
#pragma unroll
  for (int o = 32; o; o >>= 1) ss += __shfl_down(ss, o);
  __shared__ float red[2][2];
  if ((tid & 63) == 0) red[tid >> 7][(tid >> 6) & 1] = ss;
  __syncthreads();
  float tot = red[tid >> 7][0] + red[tid >> 7][1];
  float scale = rsqrtf(tot * (1.f / D_) + 1e-5f);
  float4 wv = *(const float4*)&w[t * 4];
  __hip_bfloat16 t4[4] = {__float2bfloat16(v.x * scale * wv.x),
                          __float2bfloat16(v.y * scale * wv.y),
                          __float2bfloat16(v.z * scale * wv.z),
                          __float2bfloat16(v.w * scale * wv.w)};
  *(ushort4*)&hn[(size_t)row * 512 + t * 4] = *(ushort4*)t4;
}

// ---------------------------------------------------------------- MFMA GEMM
// C[m,n] = sum_k A[m,k]*W[n,k]; A,W bf16 K-contiguous. 4 waves 2x2,
// 16x16x32 frags, BK=32, fragment-ordered LDS, XCD-bijective swizzle.
// EPI: 0 f32 store | 1 f32 += | 5 bf16 split (n<1024->auxb else auxb2) |
//      6 bf16 store auxb | 7 softplus(v+bias[n]) bf16 auxb
template <int BM, int BN, int EPI>
__global__ __launch_bounds__(256) void gemm_mfma_kernel(
    const __hip_bfloat16* __restrict__ A, int lda,
    const __hip_bfloat16* __restrict__ W, float* __restrict__ C, int ldc,
    __hip_bfloat16* __restrict__ auxb, __hip_bfloat16* __restrict__ auxb2,
    const float* __restrict__ bias, int K) {
  constexpr int FM = BM / 32, FN = BN / 32;
  __shared__ __bf16 As[2][BM * 32];
  __shared__ __bf16 Bs[2][BN * 32];
  const int tid = threadIdx.x;
  const int w = tid >> 6, l = tid & 63;
  const int gx = gridDim.x;
  const int nwg = gx * gridDim.y;
  const int wg = blockIdx.y * gx + blockIdx.x;
  const int q = nwg >> 3, r = nwg & 7;
  const int xcd = wg & 7, pos = wg >> 3;
  const int wgid =
      (xcd < r ? xcd * (q + 1) : r * (q + 1) + (xcd - r) * q) + pos;
  const int m0 = (wgid / gx) * BM, n0 = (wgid % gx) * BN;
  const int wr = w >> 1, wc = w & 1;
  const int lrow = l & 15, lk = (l >> 4) * 8;

  const size_t arow0 = (size_t)(m0 + w * 16 + lrow) * lda + lk;
  const size_t arow1 = (size_t)(m0 + (w + 4) * 16 + lrow) * lda + lk;
  const size_t brow0 = (size_t)(n0 + w * 16 + lrow) * K + lk;
  const size_t brow1 = (size_t)(n0 + (w + 4) * 16 + lrow) * K + lk;

  f32x4 acc[FM][FN];
#pragma unroll
  for (int i = 0; i < FM; ++i)
#pragma unroll
    for (int j = 0; j < FN; ++j) acc[i][j] = (f32x4)0.f;

  auto stage = [&](int bufi, int k0) {
    ASYNC_LDS16(A + arow0 + k0, &As[bufi][w * 512]);
    if constexpr (BM == 128)
      ASYNC_LDS16(A + arow1 + k0, &As[bufi][(w + 4) * 512]);
    ASYNC_LDS16(W + brow0 + k0, &Bs[bufi][w * 512]);
    if constexpr (BN == 128)
      ASYNC_LDS16(W + brow1 + k0, &Bs[bufi][(w + 4) * 512]);
  };

  stage(0, 0);
  int buf = 0;
  for (int k0 = 0; k0 < K; k0 += 32) {
    __syncthreads();
    if (k0 + 32 < K) stage(buf ^ 1, k0 + 32);
    bf16x8 af[FM], bfr[FN];
#pragma unroll
    for (int mi = 0; mi < FM; ++mi)
      af[mi] = *(bf16x8*)&As[buf][(wr * FM + mi) * 512 + l * 8];
#pragma unroll
    for (int ni = 0; ni < FN; ++ni)
      bfr[ni] = *(bf16x8*)&Bs[buf][(wc * FN + ni) * 512 + l * 8];
#pragma unroll
    for (int mi = 0; mi < FM; ++mi)
#pragma unroll
      for (int ni = 0; ni < FN; ++ni)
        acc[mi][ni] = __builtin_amdgcn_mfma_f32_16x16x32_bf16(
            af[mi], bfr[ni], acc[mi][ni], 0, 0, 0);
    buf ^= 1;
  }

#pragma unroll
  for (int mi = 0; mi < FM; ++mi) {
#pragma unroll
    for (int ni = 0; ni < FN; ++ni) {
      int row0 = m0 + (wr * FM + mi) * 16 + (l >> 4) * 4;
      int col = n0 + (wc * FN + ni) * 16 + (l & 15);
#pragma unroll
      for (int r2 = 0; r2 < 4; ++r2) {
        int row = row0 + r2;
        float v = acc[mi][ni][r2];
        if (EPI == 0) {
          C[(size_t)row * ldc + col] = v;
        } else if (EPI == 1) {
          C[(size_t)row * ldc + col] += v;
        } else if (EPI == 5) {
          if (col < 1024)
            auxb[(size_t)row * 1024 + col] = __float2bfloat16(v);
          else
            auxb2[(size_t)row * 1024 + (col - 1024)] = __float2bfloat16(v);
        } else if (EPI == 6) {
          auxb[(size_t)row * ldc + col] = __float2bfloat16(v);
        } else if (EPI == 7) {
          v += bias[col];
          v = (v > 20.f) ? v : log1pf(__expf(v));
          auxb[(size_t)row * ldc + col] = __float2bfloat16(v);
        }
      }
    }
  }
}

// ---------------------------------------------------------------- conv+silu
// 8 ed per thread; bf16 in/out; causal within each batch of 1024.
__global__ __launch_bounds__(256) void conv_silu_kernel(
    const __hip_bfloat16* __restrict__ xcb, const float* __restrict__ cw,
    const float* __restrict__ cb, __hip_bfloat16* __restrict__ out) {
  int i = blockIdx.x * 256 + threadIdx.x;  // Mc*128 threads
  int ed = (i & 127) * 8;
  int bl = i >> 7;
  int l = bl & 1023;
  float4 cwv[8];
#pragma unroll
  for (int e = 0; e < 8; ++e) cwv[e] = *(const float4*)&cw[(ed + e) * 4];
  float ac[8];
  {
    float4 c0 = *(const float4*)&cb[ed];
    float4 c1 = *(const float4*)&cb[ed + 4];
    ac[0] = c0.x; ac[1] = c0.y; ac[2] = c0.z; ac[3] = c0.w;
    ac[4] = c1.x; ac[5] = c1.y; ac[6] = c1.z; ac[7] = c1.w;
  }
#pragma unroll
  for (int j = 0; j < DC_; ++j) {
    if (l - 3 + j >= 0) {
      const __hip_bfloat16* src = &xcb[(size_t)(bl - 3 + j) * 1024 + ed];
      ushort4 a = *(const ushort4*)src;
      ushort4 b = *(const ushort4*)(src + 4);
      unsigned short xv[8] = {a.x, a.y, a.z, a.w, b.x, b.y, b.z, b.w};
#pragma unroll
      for (int e = 0; e < 8; ++e)
        ac[e] = fmaf(__bfloat162float(*(__hip_bfloat16*)&xv[e]),
                     ((const float*)&cwv[e])[j], ac[e]);
    }
  }
  __hip_bfloat16 t8[8];
#pragma unroll
  for (int e = 0; e < 8; ++e) {
    float v = ac[e] / (1.f + __expf(-ac[e]));
    t8[e] = __float2bfloat16(v);
  }
  *(ushort4*)&out[(size_t)bl * 1024 + ed] = *(ushort4*)&t8[0];
  *(ushort4*)&out[(size_t)bl * 1024 + ed + 4] = *(ushort4*)&t8[4];
}

// ---------------------------------------------------------------- scan p1
// States only: per (b, chunk of 64, 32-ed group) compute chunk-final state S
// and total delta. No y output.
__global__ __launch_bounds__(256) void scan_p1_kernel(
    const __hip_bfloat16* __restrict__ dltb, const float* __restrict__ dbc,
    const __hip_bfloat16* __restrict__ xcb, const float* __restrict__ A_log,
    float* __restrict__ S, float* __restrict__ totd) {
  const int tid = threadIdx.x;
  const int edl = tid >> 3, np = tid & 7, n0 = np * 2;
  const int g = blockIdx.x & 31;
  const int c = (blockIdx.x >> 5) & 15;
  const int b = blockIdx.x >> 9;
  const int edbase = g * 32, ed = edbase + edl;
  __shared__ __hip_bfloat16 sd[64][32], su[64][32];
  __shared__ float sbcB[64][16];
  const float An0 = -__expf(A_log[ed * 16 + n0]);
  const float An1 = -__expf(A_log[ed * 16 + n0 + 1]);
  const int w = tid >> 6;
  const int ur = tid >> 2, uc = (tid & 3) * 8;  // bf16: 4 lanes/row
  const size_t row0 = (size_t)b * 1024 + c * 64;

  ASYNC_LDS16(&dltb[(row0 + ur) * 1024 + edbase + uc], &sd[w * 16][0]);
  ASYNC_LDS16(&xcb[(row0 + ur) * 1024 + edbase + uc], &su[w * 16][0]);
  ASYNC_LDS16(&dbc[(row0 + ur) * 64 + 32 + (tid & 3) * 4], &sbcB[w * 16][0]);

  float h0 = 0.f, h1 = 0.f, cd = 0.f;
  __syncthreads();
#pragma unroll 16
  for (int t = 0; t < 64; ++t) {
    float dv = __bfloat162float(sd[t][edl]);
    float u = __bfloat162float(su[t][edl]);
    float2 Bp = *(float2*)&sbcB[t][n0];
    float du = dv * u;
    h0 = fmaf(__expf(dv * An0), h0, du * Bp.x);
    h1 = fmaf(__expf(dv * An1), h1, du * Bp.y);
    cd += dv;
  }
  size_t sidx = (((size_t)b * 16 + c) * 1024 + ed) * 16 + n0;
  *(float2*)&S[sidx] = make_float2(h0, h1);
  if (np == 0) totd[((size_t)b * 16 + c) * 1024 + ed] = cd;
}

// ---------------------------------------------------------------- scan p2
__global__ __launch_bounds__(256) void scan_p2_kernel(
    const float* __restrict__ S, const float* __restrict__ totd,
    const float* __restrict__ A_log, float* __restrict__ HP) {
  int t = blockIdx.x * 256 + threadIdx.x;
  int n = t & 15, ed = (t >> 4) & 1023;
  int b = t >> 14;
  float An = -__expf(A_log[ed * 16 + n]);
  float H = 0.f;
#pragma unroll
  for (int c = 0; c < 16; ++c) {
    size_t i = ((size_t)b * 16 + c) * 1024 + ed;
    HP[i * 16 + n] = H;
    H = fmaf(__expf(An * totd[i]), H, S[i * 16 + n]);
  }
}

// ---------------------------------------------------------------- scan p3
// Full rescan from exact initial state HP; emits gated bf16 y (in-place
// over z: z staged to LDS before any y store).
__global__ __launch_bounds__(256) void scan_p3_kernel(
    const __hip_bfloat16* __restrict__ dltb, const float* __restrict__ dbc,
    const __hip_bfloat16* __restrict__ xcb, const __hip_bfloat16* __restrict__ zb,
    const float* __restrict__ A_log, const float* __restrict__ Dp,
    const float* __restrict__ HP, __hip_bfloat16* __restrict__ y) {
  const int tid = threadIdx.x;
  const int edl = tid >> 3, np = tid & 7, n0 = np * 2;
  const int g = blockIdx.x & 31;
  const int c = (blockIdx.x >> 5) & 15;
  const int b = blockIdx.x >> 9;
  const int edbase = g * 32, ed = edbase + edl;
  __shared__ __hip_bfloat16 sd[64][32], su[64][32], sz[64][32];
  __shared__ float sbc[64][32];
  __shared__ float sy[32][32];
  const float An0 = -__expf(A_log[ed * 16 + n0]);
  const float An1 = -__expf(A_log[ed * 16 + n0 + 1]);
  const float Dv8 = Dp[ed] * 0.125f;
  const int w = tid >> 6;
  const int sr = tid >> 3, sc = (tid & 7) * 4;  // f32 32/row: 8 lanes/row
  const int ur = tid >> 2, uc = (tid & 3) * 8;  // bf16 32/row: 4 lanes/row
  const size_t row0 = (size_t)b * 1024 + c * 64;

  ASYNC_LDS16(&dltb[(row0 + ur) * 1024 + edbase + uc], &sd[w * 16][0]);
  ASYNC_LDS16(&xcb[(row0 + ur) * 1024 + edbase + uc], &su[w * 16][0]);
  ASYNC_LDS16(&zb[(row0 + ur) * 1024 + edbase + uc], &sz[w * 16][0]);
  ASYNC_LDS16(&dbc[(row0 + sr) * 64 + 32 + sc], &sbc[w * 8][0]);
  ASYNC_LDS16(&dbc[(row0 + 32 + sr) * 64 + 32 + sc], &sbc[32 + w * 8][0]);

  float2 hp = *(const float2*)&HP[(((size_t)b * 16 + c) * 1024 + ed) * 16 + n0];
  float h0 = hp.x, h1 = hp.y;
  __syncthreads();
#pragma unroll
  for (int tl = 0; tl < 2; ++tl) {
    float preg[32];
#pragma unroll
    for (int t = 0; t < 32; ++t) {
      const int tt = tl * 32 + t;
      float dv = __bfloat162float(sd[tt][edl]);
      float u = __bfloat162float(su[tt][edl]);
      float2 Bp = *(float2*)&sbc[tt][n0];
      float2 Cp = *(float2*)&sbc[tt][16 + n0];
      float du = dv * u;
      h0 = fmaf(__expf(dv * An0), h0, du * Bp.x);
      h1 = fmaf(__expf(dv * An1), h1, du * Bp.y);
      preg[t] = fmaf(Dv8, u, fmaf(h0, Cp.x, h1 * Cp.y));
    }
#pragma unroll
    for (int t = 0; t < 32; ++t) {
      float v = preg[t];
      v += __shfl_xor(v, 1);
      v += __shfl_xor(v, 2);
      v += __shfl_xor(v, 4);
      if (np == 0) sy[t][edl] = v;
    }
    __syncthreads();
    {
      size_t row = row0 + tl * 32 + sr;
      float4 v = *(float4*)&sy[sr][sc];
      ushort4 zv = *(ushort4*)&sz[tl * 32 + sr][sc];
      float vo[4] = {v.x, v.y, v.z, v.w};
      unsigned short zo[4] = {zv.x, zv.y, zv.z, zv.w};
      __hip_bfloat16 t4[4];
#pragma unroll
      for (int j = 0; j < 4; ++j) {
        float zz = __bfloat162float(*(__hip_bfloat16*)&zo[j]);
        float gt = zz / (1.f + __expf(-zz));
        t4[j] = __float2bfloat16(vo[j] * gt);
      }
      *(ushort4*)&y[row * 1024 + edbase + sc] = *(ushort4*)t4;
    }
    __syncthreads();
  }
}

// ---------------------------------------------------------------- head
__global__ __launch_bounds__(256) void head_kernel(
    const float* __restrict__ h, const float* __restrict__ hw,
    const float* __restrict__ hb, float* __restrict__ out) {
  int hc = blockIdx.x * 256 + threadIdx.x;
  int b = blockIdx.y;
  __shared__ float hs[D_];
  for (int d = threadIdx.x; d < D_; d += 256)
    hs[d] = h[((size_t)(b << 10) + 1023) * D_ + d];
  __syncthreads();
  float s = hb[hc];
#pragma unroll 16
  for (int d = 0; d < D_; d += 4) {
    float4 wv = *(const float4*)&hw[(size_t)hc * D_ + d];
    s = fmaf(hs[d], wv.x, s);
    s = fmaf(hs[d + 1], wv.y, s);
    s = fmaf(hs[d + 2], wv.z, s);
    s = fmaf(hs[d + 3], wv.w, s);
  }
  int t = hc >> 5, c = hc & 31;
  out[(size_t)b * 3072 + c * 96 + t] = s;
}

// ---------------------------------------------------------------- launch
extern "C" void kernel_launch(void* const* d_in, const int* in_sizes, int n_in,
                              void* d_out, int out_size, void* d_ws,
                              size_t ws_size, hipStream_t stream) {
  const float* x = (const float*)d_in[0];
  const float* embed_w = (const float*)d_in[1];
  const float* embed_b = (const float*)d_in[2];
  const float* norm_w = (const float*)d_in[3];
  const float* in_proj_w = (const float*)d_in[4];
  const float* conv_w = (const float*)d_in[5];
  const float* conv_b = (const float*)d_in[6];
  const float* x_proj_w = (const float*)d_in[7];
  const float* dt_proj_w = (const float*)d_in[8];
  const float* dt_proj_b = (const float*)d_in[9];
  const float* A_log = (const float*)d_in[10];
  const float* Dp = (const float*)d_in[11];
  const float* out_proj_w = (const float*)d_in[12];
  const float* head_w = (const float*)d_in[13];
  const float* head_b = (const float*)d_in[14];
  float* out = (float*)d_out;

  // fixed: h 33.5MB | wbi 8.4 | wbo 4.2 | wxp 0.5 | wdtbf 0.25 | wxpT 0.25 |
  //        wcombbf 8.4 | per-cb: S + HP (cb MB each) + totd
  // chunk rows: hn 1024B | buf1 2048 (xc_raw->dlt) | buf2 2048 (z->y) |
  //             xcsbf 2048 | dbc 256  = 7424 B/row
  const size_t fixed0 = 33554432ull + 8388608ull + 4194304ull + 524288ull +
                        262144ull + 262144ull + 8388608ull;
  auto need = [&](int cbx) {
    return fixed0 + (size_t)cbx * (2ull * 1048576 + 65536) +
           (size_t)cbx * 1024 * 7424;
  };
  int cb = 16;
  while (cb > 1 && need(cb) > ws_size) cb >>= 1;
  if (need(cb) > ws_size) return;
  const int Mc = cb * 1024;
  const int nchunks = 16 / cb;

  char* p = (char*)d_ws;
  float* h = (float*)p;                        p += 33554432ull;
  __hip_bfloat16* wbi = (__hip_bfloat16*)p;    p += 8388608ull;
  __hip_bfloat16* wbo = (__hip_bfloat16*)p;    p += 4194304ull;
  __hip_bfloat16* wxp = (__hip_bfloat16*)p;    p += 524288ull;
  __hip_bfloat16* wdtbf = (__hip_bfloat16*)p;  p += 262144ull;
  __hip_bfloat16* wxpT = (__hip_bfloat16*)p;   p += 262144ull;
  __hip_bfloat16* wcombbf = (__hip_bfloat16*)p; p += 8388608ull;
  float* S = (float*)p;                        p += (size_t)cb * 1048576;
  float* HP = (float*)p;                       p += (size_t)cb * 1048576;
  float* totd = (float*)p;                     p += (size_t)cb * 65536;
  __hip_bfloat16* hn = (__hip_bfloat16*)p;     p += (size_t)Mc * 1024;
  __hip_bfloat16* buf1 = (__hip_bfloat16*)p;   p += (size_t)Mc * 2048;
  __hip_bfloat16* buf2 = (__hip_bfloat16*)p;   p += (size_t)Mc * 2048;
  __hip_bfloat16* xcsbf = (__hip_bfloat16*)p;  p += (size_t)Mc * 2048;
  float* dbc = (float*)p;

  cvt_bf16_kernel<<<4096, 256, 0, stream>>>(in_proj_w, wbi, 1048576);
  cvt_bf16_kernel<<<2048, 256, 0, stream>>>(out_proj_w, wbo, 524288);
  cvt_bf16_kernel<<<256, 256, 0, stream>>>(x_proj_w, wxp, 65536);
  cvt_bf16_kernel<<<128, 256, 0, stream>>>(dt_proj_w, wdtbf, 32768);
  transpose_xp_kernel<<<512, 256, 0, stream>>>(x_proj_w, wxpT);
  // wcomb[i] = wdt @ wxp[:32]  (1024x1024, K=32), bf16 out
  for (int i = 0; i < 4; ++i)
    gemm_mfma_kernel<128, 128, 6><<<dim3(8, 8), 256, 0, stream>>>(
        wdtbf + (size_t)i * 32768, 32, wxpT + (size_t)i * 32768, nullptr,
        1024, wcombbf + (size_t)i * 1048576, nullptr, nullptr, 32);
  embed_kernel<<<dim3(16, 16), 256, 0, stream>>>(x, embed_w, embed_b, h);

  for (int i = 0; i < 4; ++i) {
    const float* Ai = A_log + (size_t)i * ED_ * N_;
    for (int ch = 0; ch < nchunks; ++ch) {
      float* hc = h + (size_t)ch * Mc * D_;
      rmsnorm_kernel<<<Mc / 2, 256, 0, stream>>>(hc, norm_w + i * D_, hn);
      // in_proj: n<1024 -> buf1 (xc_raw), n>=1024 -> buf2 (z)
      gemm_mfma_kernel<128, 128, 5><<<dim3(16, Mc / 128), 256, 0, stream>>>(
          hn, D_, wbi + (size_t)i * 1048576, nullptr, 0, buf1, buf2, nullptr,
          D_);
      conv_silu_kernel<<<Mc / 2, 256, 0, stream>>>(
          buf1, conv_w + i * ED_ * DC_, conv_b + i * ED_, xcsbf);
      // x_proj: dbc f32 (need cols 32..63: B,C)
      gemm_mfma_kernel<64, 64, 0><<<dim3(1, Mc / 64), 256, 0, stream>>>(
          xcsbf, ED_, wxp + (size_t)i * 65536, dbc, 64, nullptr, nullptr,
          nullptr, ED_);
      // delta = softplus(xcs @ wcomb^T + dt_b) -> buf1 bf16 (over dead xc_raw)
      gemm_mfma_kernel<128, 128, 7><<<dim3(8, Mc / 128), 256, 0, stream>>>(
          xcsbf, ED_, wcombbf + (size_t)i * 1048576, nullptr, 1024, buf1,
          nullptr, dt_proj_b + i * ED_, ED_);
      scan_p1_kernel<<<cb * 512, 256, 0, stream>>>(buf1, dbc, xcsbf, Ai, S,
                                                   totd);
      scan_p2_kernel<<<cb * 64, 256, 0, stream>>>(S, totd, Ai, HP);
      // p3: y (bf16) written in-place over z (buf2)
      scan_p3_kernel<<<cb * 512, 256, 0, stream>>>(
          buf1, dbc, xcsbf, buf2, Ai, Dp + i * ED_, HP, buf2);
      // h += y @ out_proj^T
      gemm_mfma_kernel<128, 128, 1><<<dim3(4, Mc / 128), 256, 0, stream>>>(
          buf2, ED_, wbo + (size_t)i * 524288, hc, D_, nullptr, nullptr,
          nullptr, ED_);
    }
  }

  head_kernel<<<dim3(12, B_), 256, 0, stream>>>(h, head_w, head_b, out);
}

// Round 7
// 1996.855 us; speedup vs baseline: 5.6452x; 1.3037x over previous
//
#include <hip/hip_runtime.h>
#include <hip/hip_bf16.h>

// MultiVForecaster: 4-layer Mamba (B=16, L=1024, D=512, ED=1024, N=16).
// Round 7: scan with all 16 states per thread (no cross-lane reduce),
// x_proj folded into the delta GEMM (wcat = [wcomb | wxp[32:64] | pad]),
// silu(z) fused into in_proj epilogue.

#define B_ 16
#define L_ 1024
#define D_ 512
#define ED_ 1024
#define N_ 16
#define DR_ 32
#define DC_ 4
#define BL_ (B_ * L_)

typedef __attribute__((ext_vector_type(8))) __bf16 bf16x8;
typedef __attribute__((ext_vector_type(4))) float f32x4;

#define ASYNC_LDS16(G, L)                                                      \
  __builtin_amdgcn_global_load_lds(                                            \
      (const __attribute__((address_space(1))) void*)(G),                      \
      (__attribute__((address_space(3))) void*)(L), 16, 0, 0)

__device__ __forceinline__ float bf2f(unsigned short v) {
  unsigned int u = (unsigned int)v << 16;
  return __builtin_bit_cast(float, u);
}

// ---------------------------------------------------------------- embed
__global__ __launch_bounds__(256) void embed_kernel(
    const float* __restrict__ x, const float* __restrict__ w,
    const float* __restrict__ bias, float* __restrict__ h) {
  __shared__ float xs[64][36];
  __shared__ float ws[32][513];
  const int tid = threadIdx.x;
  const int b = blockIdx.y, l0 = blockIdx.x * 64;
  for (int f = tid; f < 16384; f += 256) {
    int d = f >> 5, i = f & 31;
    ws[i][d] = w[f];
  }
  for (int f = tid; f < 2048; f += 256) {
    int i = f >> 6, l = f & 63;
    xs[l][i] = x[b * 32768 + i * 1024 + l0 + l];
  }
  const int d0 = tid, d1 = tid + 256;
  __syncthreads();
  float wr0[32], wr1[32];
#pragma unroll
  for (int i = 0; i < 32; ++i) {
    wr0[i] = ws[i][d0];
    wr1[i] = ws[i][d1];
  }
  const float b0 = bias[d0], b1 = bias[d1];
  for (int l = 0; l < 64; ++l) {
    float a0 = b0, a1 = b1;
#pragma unroll
    for (int q = 0; q < 8; ++q) {
      float4 xv = *(float4*)&xs[l][q * 4];
      a0 = fmaf(xv.x, wr0[q * 4], a0);
      a1 = fmaf(xv.x, wr1[q * 4], a1);
      a0 = fmaf(xv.y, wr0[q * 4 + 1], a0);
      a1 = fmaf(xv.y, wr1[q * 4 + 1], a1);
      a0 = fmaf(xv.z, wr0[q * 4 + 2], a0);
      a1 = fmaf(xv.z, wr1[q * 4 + 2], a1);
      a0 = fmaf(xv.w, wr0[q * 4 + 3], a0);
      a1 = fmaf(xv.w, wr1[q * 4 + 3], a1);
    }
    size_t row = (size_t)(b << 10) + l0 + l;
    h[row * 512 + d0] = a0;
    h[row * 512 + d1] = a1;
  }
}

// ---------------------------------------------------------------- cvt f32->bf16
__global__ __launch_bounds__(256) void cvt_bf16_kernel(
    const float* __restrict__ src, __hip_bfloat16* __restrict__ dst, int n4) {
  int i = blockIdx.x * 256 + threadIdx.x;
  if (i < n4) {
    float4 v = *(const float4*)&src[(size_t)i * 4];
    __hip_bfloat16 t4[4] = {__float2bfloat16(v.x), __float2bfloat16(v.y),
                            __float2bfloat16(v.z), __float2bfloat16(v.w)};
    *(ushort4*)&dst[(size_t)i * 4] = *(ushort4*)t4;
  }
}

// wxpT[i][k,r] = x_proj_w[i][r,k], r<32 (dt_rank rows)
__global__ __launch_bounds__(256) void transpose_xp_kernel(
    const float* __restrict__ xp, __hip_bfloat16* __restrict__ xpT) {
  int t = blockIdx.x * 256 + threadIdx.x;
  int r = t & 31, k = (t >> 5) & 1023, i = t >> 15;
  xpT[i * 32768 + k * 32 + r] = __float2bfloat16(xp[i * 65536 + r * 1024 + k]);
}

// wcat rows 1024..1087: [1024..1055] = xp rows 32..63 (B,C); rest zero pad.
__global__ __launch_bounds__(256) void wcat_tail_kernel(
    const float* __restrict__ xp, __hip_bfloat16* __restrict__ wcat) {
  int t = blockIdx.x * 256 + threadIdx.x;  // 4 * 64 * 1024
  int k = t & 1023, row = (t >> 10) & 63, i = t >> 16;
  float v = (row < 32) ? xp[i * 65536 + (32 + row) * 1024 + k] : 0.f;
  wcat[(size_t)i * 1114112 + (size_t)(1024 + row) * 1024 + k] =
      __float2bfloat16(v);
}

// ---------------------------------------------------------------- rmsnorm
__global__ __launch_bounds__(256) void rmsnorm_kernel(
    const float* __restrict__ h, const float* __restrict__ w,
    __hip_bfloat16* __restrict__ hn) {
  const int tid = threadIdx.x;
  const int row = blockIdx.x * 2 + (tid >> 7);
  const int t = tid & 127;
  float4 v = *(const float4*)&h[(size_t)row * 512 + t * 4];
  float ss = v.x * v.x + v.y * v.y + v.z * v.z + v.w * v.w;
#pragma unroll
  for (int o = 32; o; o >>= 1) ss += __shfl_down(ss, o);
  __shared__ float red[2][2];
  if ((tid & 63) == 0) red[tid >> 7][(tid >> 6) & 1] = ss;
  __syncthreads();
  float tot = red[tid >> 7][0] + red[tid >> 7][1];
  float scale = rsqrtf(tot * (1.f / D_) + 1e-5f);
  float4 wv = *(const float4*)&w[t * 4];
  __hip_bfloat16 t4[4] = {__float2bfloat16(v.x * scale * wv.x),
                          __float2bfloat16(v.y * scale * wv.y),
                          __float2bfloat16(v.z * scale * wv.z),
                          __float2bfloat16(v.w * scale * wv.w)};
  *(ushort4*)&hn[(size_t)row * 512 + t * 4] = *(ushort4*)t4;
}

// ---------------------------------------------------------------- MFMA GEMM
// C[m,n] = sum_k A[m,k]*W[n,k]; bf16 K-contiguous; 4 waves 2x2, 16x16x32,
// BK=32, fragment-ordered LDS, XCD-bijective swizzle.
// EPI: 1 f32 += | 5 bf16: col<1024->auxb (raw), col>=1024->auxb2 = silu(v)
//      6 bf16 store auxb (ldc) | 8 fused: col<1024 softplus(v+bias)->auxb,
//      1024<=col<1056 -> f32 C[row*32+col-1024]
template <int BM, int BN, int EPI>
__global__ __launch_bounds__(256) void gemm_mfma_kernel(
    const __hip_bfloat16* __restrict__ A, int lda,
    const __hip_bfloat16* __restrict__ W, float* __restrict__ C, int ldc,
    __hip_bfloat16* __restrict__ auxb, __hip_bfloat16* __restrict__ auxb2,
    const float* __restrict__ bias, int K) {
  constexpr int FM = BM / 32, FN = BN / 32;
  __shared__ __bf16 As[2][BM * 32];
  __shared__ __bf16 Bs[2][BN * 32];
  const int tid = threadIdx.x;
  const int w = tid >> 6, l = tid & 63;
  const int gx = gridDim.x;
  const int nwg = gx * gridDim.y;
  const int wg = blockIdx.y * gx + blockIdx.x;
  const int q = nwg >> 3, r = nwg & 7;
  const int xcd = wg & 7, pos = wg >> 3;
  const int wgid =
      (xcd < r ? xcd * (q + 1) : r * (q + 1) + (xcd - r) * q) + pos;
  const int m0 = (wgid / gx) * BM, n0 = (wgid % gx) * BN;
  const int wr = w >> 1, wc = w & 1;
  const int lrow = l & 15, lk = (l >> 4) * 8;

  const size_t arow0 = (size_t)(m0 + w * 16 + lrow) * lda + lk;
  const size_t arow1 = (size_t)(m0 + (w + 4) * 16 + lrow) * lda + lk;
  const size_t brow0 = (size_t)(n0 + w * 16 + lrow) * K + lk;
  const size_t brow1 = (size_t)(n0 + (w + 4) * 16 + lrow) * K + lk;

  f32x4 acc[FM][FN];
#pragma unroll
  for (int i = 0; i < FM; ++i)
#pragma unroll
    for (int j = 0; j < FN; ++j) acc[i][j] = (f32x4)0.f;

  auto stage = [&](int bufi, int k0) {
    ASYNC_LDS16(A + arow0 + k0, &As[bufi][w * 512]);
    if constexpr (BM == 128)
      ASYNC_LDS16(A + arow1 + k0, &As[bufi][(w + 4) * 512]);
    ASYNC_LDS16(W + brow0 + k0, &Bs[bufi][w * 512]);
    if constexpr (BN == 128)
      ASYNC_LDS16(W + brow1 + k0, &Bs[bufi][(w + 4) * 512]);
  };

  stage(0, 0);
  int buf = 0;
  for (int k0 = 0; k0 < K; k0 += 32) {
    __syncthreads();
    if (k0 + 32 < K) stage(buf ^ 1, k0 + 32);
    bf16x8 af[FM], bfr[FN];
#pragma unroll
    for (int mi = 0; mi < FM; ++mi)
      af[mi] = *(bf16x8*)&As[buf][(wr * FM + mi) * 512 + l * 8];
#pragma unroll
    for (int ni = 0; ni < FN; ++ni)
      bfr[ni] = *(bf16x8*)&Bs[buf][(wc * FN + ni) * 512 + l * 8];
#pragma unroll
    for (int mi = 0; mi < FM; ++mi)
#pragma unroll
      for (int ni = 0; ni < FN; ++ni)
        acc[mi][ni] = __builtin_amdgcn_mfma_f32_16x16x32_bf16(
            af[mi], bfr[ni], acc[mi][ni], 0, 0, 0);
    buf ^= 1;
  }

#pragma unroll
  for (int mi = 0; mi < FM; ++mi) {
#pragma unroll
    for (int ni = 0; ni < FN; ++ni) {
      int row0 = m0 + (wr * FM + mi) * 16 + (l >> 4) * 4;
      int col = n0 + (wc * FN + ni) * 16 + (l & 15);
#pragma unroll
      for (int r2 = 0; r2 < 4; ++r2) {
        int row = row0 + r2;
        float v = acc[mi][ni][r2];
        if (EPI == 1) {
          C[(size_t)row * ldc + col] += v;
        } else if (EPI == 5) {
          if (col < 1024) {
            auxb[(size_t)row * 1024 + col] = __float2bfloat16(v);
          } else {
            float g = v / (1.f + __expf(-v));
            auxb2[(size_t)row * 1024 + (col - 1024)] = __float2bfloat16(g);
          }
        } else if (EPI == 6) {
          auxb[(size_t)row * ldc + col] = __float2bfloat16(v);
        } else if (EPI == 8) {
          if (col < 1024) {
            v += bias[col];
            v = (v > 20.f) ? v : log1pf(__expf(v));
            auxb[(size_t)row * 1024 + col] = __float2bfloat16(v);
          } else if (col < 1056) {
            C[(size_t)row * 32 + (col - 1024)] = v;
          }
        }
      }
    }
  }
}

// ---------------------------------------------------------------- conv+silu
__global__ __launch_bounds__(256) void conv_silu_kernel(
    const __hip_bfloat16* __restrict__ xcb, const float* __restrict__ cw,
    const float* __restrict__ cb, __hip_bfloat16* __restrict__ out) {
  int i = blockIdx.x * 256 + threadIdx.x;
  int ed = (i & 127) * 8;
  int bl = i >> 7;
  int l = bl & 1023;
  float4 cwv[8];
#pragma unroll
  for (int e = 0; e < 8; ++e) cwv[e] = *(const float4*)&cw[(ed + e) * 4];
  float ac[8];
  {
    float4 c0 = *(const float4*)&cb[ed];
    float4 c1 = *(const float4*)&cb[ed + 4];
    ac[0] = c0.x; ac[1] = c0.y; ac[2] = c0.z; ac[3] = c0.w;
    ac[4] = c1.x; ac[5] = c1.y; ac[6] = c1.z; ac[7] = c1.w;
  }
#pragma unroll
  for (int j = 0; j < DC_; ++j) {
    if (l - 3 + j >= 0) {
      const __hip_bfloat16* src = &xcb[(size_t)(bl - 3 + j) * 1024 + ed];
      ushort4 a = *(const ushort4*)src;
      ushort4 b = *(const ushort4*)(src + 4);
      unsigned short xv[8] = {a.x, a.y, a.z, a.w, b.x, b.y, b.z, b.w};
#pragma unroll
      for (int e = 0; e < 8; ++e)
        ac[e] = fmaf(bf2f(xv[e]), ((const float*)&cwv[e])[j], ac[e]);
    }
  }
  __hip_bfloat16 t8[8];
#pragma unroll
  for (int e = 0; e < 8; ++e) {
    float v = ac[e] / (1.f + __expf(-ac[e]));
    t8[e] = __float2bfloat16(v);
  }
  *(ushort4*)&out[(size_t)bl * 1024 + ed] = *(ushort4*)&t8[0];
  *(ushort4*)&out[(size_t)bl * 1024 + ed + 4] = *(ushort4*)&t8[4];
}

// ---------------------------------------------------------------- scan p1
// Thread owns one ed with all 16 states in registers. States-only output.
// dbc layout: [row][32]: B = cols 0..15, C = cols 16..31.
__global__ __launch_bounds__(256) void scan_p1_kernel(
    const unsigned short* __restrict__ dlt, const float* __restrict__ dbc,
    const unsigned short* __restrict__ xc, const float* __restrict__ A_log,
    float* __restrict__ S, float* __restrict__ totd) {
  const int tid = threadIdx.x;
  const int ed = blockIdx.x * 256 + tid;
  const int c = blockIdx.y, b = blockIdx.z;
  const size_t row0 = ((size_t)b << 10) + c * 64;
  __shared__ float sB[64][16];
  {
    const int w = tid >> 6, l = tid & 63;
    ASYNC_LDS16(&dbc[(row0 + w * 16 + (l >> 2)) * 32 + (l & 3) * 4],
                &sB[w * 16][0]);
  }
  float An[16], h[16];
#pragma unroll
  for (int n = 0; n < 16; n += 4) {
    float4 a = *(const float4*)&A_log[ed * 16 + n];
    An[n] = -__expf(a.x);
    An[n + 1] = -__expf(a.y);
    An[n + 2] = -__expf(a.z);
    An[n + 3] = -__expf(a.w);
    h[n] = h[n + 1] = h[n + 2] = h[n + 3] = 0.f;
  }
  float cd = 0.f;
  size_t gi = row0 * 1024 + ed;
  __syncthreads();
  unsigned short nd = dlt[gi], nu = xc[gi];
#pragma unroll 4
  for (int t = 0; t < 64; ++t) {
    float dv = bf2f(nd), u = bf2f(nu);
    if (t < 63) {
      nd = dlt[gi + 1024];
      nu = xc[gi + 1024];
    }
    float du = dv * u;
    cd += dv;
    float Bv[16];
    *(float4*)&Bv[0] = *(float4*)&sB[t][0];
    *(float4*)&Bv[4] = *(float4*)&sB[t][4];
    *(float4*)&Bv[8] = *(float4*)&sB[t][8];
    *(float4*)&Bv[12] = *(float4*)&sB[t][12];
#pragma unroll
    for (int n = 0; n < 16; ++n)
      h[n] = fmaf(__expf(dv * An[n]), h[n], du * Bv[n]);
    gi += 1024;
  }
  const size_t so = (((size_t)b * 16 + c) * 1024 + ed) * 16;
  *(float4*)&S[so] = make_float4(h[0], h[1], h[2], h[3]);
  *(float4*)&S[so + 4] = make_float4(h[4], h[5], h[6], h[7]);
  *(float4*)&S[so + 8] = make_float4(h[8], h[9], h[10], h[11]);
  *(float4*)&S[so + 12] = make_float4(h[12], h[13], h[14], h[15]);
  totd[((size_t)b * 16 + c) * 1024 + ed] = cd;
}

// ---------------------------------------------------------------- scan p2
__global__ __launch_bounds__(256) void scan_p2_kernel(
    const float* __restrict__ S, const float* __restrict__ totd,
    const float* __restrict__ A_log, float* __restrict__ HP) {
  int t = blockIdx.x * 256 + threadIdx.x;
  int n = t & 15, ed = (t >> 4) & 1023;
  int b = t >> 14;
  float An = -__expf(A_log[ed * 16 + n]);
  float H = 0.f;
#pragma unroll
  for (int c = 0; c < 16; ++c) {
    size_t i = ((size_t)b * 16 + c) * 1024 + ed;
    HP[i * 16 + n] = H;
    H = fmaf(__expf(An * totd[i]), H, S[i * 16 + n]);
  }
}

// ---------------------------------------------------------------- scan p3
// Rescan from exact chunk-initial state HP; per-thread 16-state dot with C;
// gate with g = silu(z) (read) and overwrite same buffer with bf16 y.
__global__ __launch_bounds__(256) void scan_p3_kernel(
    const unsigned short* __restrict__ dlt, const float* __restrict__ dbc,
    const unsigned short* __restrict__ xc, const float* __restrict__ A_log,
    const float* __restrict__ Dp, const float* __restrict__ HP,
    unsigned short* __restrict__ yg) {
  const int tid = threadIdx.x;
  const int ed = blockIdx.x * 256 + tid;
  const int c = blockIdx.y, b = blockIdx.z;
  const size_t row0 = ((size_t)b << 10) + c * 64;
  __shared__ float sBC[64][32];
  {
    const int w = tid >> 6, l = tid & 63;
    ASYNC_LDS16(&dbc[(row0 + w * 16 + (l >> 3)) * 32 + (l & 7) * 4],
                &sBC[w * 16][0]);
    ASYNC_LDS16(&dbc[(row0 + w * 16 + 8 + (l >> 3)) * 32 + (l & 7) * 4],
                &sBC[w * 16 + 8][0]);
  }
  float An[16], h[16];
  const size_t ho = (((size_t)b * 16 + c) * 1024 + ed) * 16;
#pragma unroll
  for (int n = 0; n < 16; n += 4) {
    float4 a = *(const float4*)&A_log[ed * 16 + n];
    An[n] = -__expf(a.x);
    An[n + 1] = -__expf(a.y);
    An[n + 2] = -__expf(a.z);
    An[n + 3] = -__expf(a.w);
    *(float4*)&h[n] = *(const float4*)&HP[ho + n];
  }
  const float Dv = Dp[ed];
  size_t gi = row0 * 1024 + ed;
  __syncthreads();
  unsigned short nd = dlt[gi], nu = xc[gi], ng = yg[gi];
#pragma unroll 2
  for (int t = 0; t < 64; ++t) {
    float dv = bf2f(nd), u = bf2f(nu), g = bf2f(ng);
    if (t < 63) {
      nd = dlt[gi + 1024];
      nu = xc[gi + 1024];
      ng = yg[gi + 1024];
    }
    float du = dv * u;
    float y = Dv * u;
    float Bv[16], Cv[16];
    *(float4*)&Bv[0] = *(float4*)&sBC[t][0];
    *(float4*)&Bv[4] = *(float4*)&sBC[t][4];
    *(float4*)&Bv[8] = *(float4*)&sBC[t][8];
    *(float4*)&Bv[12] = *(float4*)&sBC[t][12];
    *(float4*)&Cv[0] = *(float4*)&sBC[t][16];
    *(float4*)&Cv[4] = *(float4*)&sBC[t][20];
    *(float4*)&Cv[8] = *(float4*)&sBC[t][24];
    *(float4*)&Cv[12] = *(float4*)&sBC[t][28];
#pragma unroll
    for (int n = 0; n < 16; ++n) {
      h[n] = fmaf(__expf(dv * An[n]), h[n], du * Bv[n]);
      y = fmaf(h[n], Cv[n], y);
    }
    __hip_bfloat16 yb = __float2bfloat16(y * g);
    yg[gi] = *(unsigned short*)&yb;
    gi += 1024;
  }
}

// ---------------------------------------------------------------- head
__global__ __launch_bounds__(256) void head_kernel(
    const float* __restrict__ h, const float* __restrict__ hw,
    const float* __restrict__ hb, float* __restrict__ out) {
  int hc = blockIdx.x * 256 + threadIdx.x;
  int b = blockIdx.y;
  __shared__ float hs[D_];
  for (int d = threadIdx.x; d < D_; d += 256)
    hs[d] = h[((size_t)(b << 10) + 1023) * D_ + d];
  __syncthreads();
  float s = hb[hc];
#pragma unroll 16
  for (int d = 0; d < D_; d += 4) {
    float4 wv = *(const float4*)&hw[(size_t)hc * D_ + d];
    s = fmaf(hs[d], wv.x, s);
    s = fmaf(hs[d + 1], wv.y, s);
    s = fmaf(hs[d + 2], wv.z, s);
    s = fmaf(hs[d + 3], wv.w, s);
  }
  int t = hc >> 5, c = hc & 31;
  out[(size_t)b * 3072 + c * 96 + t] = s;
}

// ---------------------------------------------------------------- launch
extern "C" void kernel_launch(void* const* d_in, const int* in_sizes, int n_in,
                              void* d_out, int out_size, void* d_ws,
                              size_t ws_size, hipStream_t stream) {
  const float* x = (const float*)d_in[0];
  const float* embed_w = (const float*)d_in[1];
  const float* embed_b = (const float*)d_in[2];
  const float* norm_w = (const float*)d_in[3];
  const float* in_proj_w = (const float*)d_in[4];
  const float* conv_w = (const float*)d_in[5];
  const float* conv_b = (const float*)d_in[6];
  const float* x_proj_w = (const float*)d_in[7];
  const float* dt_proj_w = (const float*)d_in[8];
  const float* dt_proj_b = (const float*)d_in[9];
  const float* A_log = (const float*)d_in[10];
  const float* Dp = (const float*)d_in[11];
  const float* out_proj_w = (const float*)d_in[12];
  const float* head_w = (const float*)d_in[13];
  const float* head_b = (const float*)d_in[14];
  float* out = (float*)d_out;

  // fixed: h 33.5MB | wbi 8.39 | wbo 4.19 | wxpT .26 | wdtbf .26 | wcat 8.91
  // per-cb: S cb*1MB + HP cb*1MB + totd cb*64KB
  // rows: hn 1024 | buf1 2048 | buf2 2048 | xcsbf 2048 | dbc 128 = 7296 B
  const size_t fixed0 = 33554432ull + 8388608ull + 4194304ull + 262144ull +
                        262144ull + 8912896ull;
  auto need = [&](int cbx) {
    return fixed0 + (size_t)cbx * (2ull * 1048576 + 65536) +
           (size_t)cbx * 1024 * 7296;
  };
  int cb = 16;
  while (cb > 1 && need(cb) > ws_size) cb >>= 1;
  if (need(cb) > ws_size) return;
  const int Mc = cb * 1024;
  const int nchunks = 16 / cb;

  char* p = (char*)d_ws;
  float* h = (float*)p;                         p += 33554432ull;
  __hip_bfloat16* wbi = (__hip_bfloat16*)p;     p += 8388608ull;
  __hip_bfloat16* wbo = (__hip_bfloat16*)p;     p += 4194304ull;
  __hip_bfloat16* wxpT = (__hip_bfloat16*)p;    p += 262144ull;
  __hip_bfloat16* wdtbf = (__hip_bfloat16*)p;   p += 262144ull;
  __hip_bfloat16* wcat = (__hip_bfloat16*)p;    p += 8912896ull;
  float* S = (float*)p;                         p += (size_t)cb * 1048576;
  float* HP = (float*)p;                        p += (size_t)cb * 1048576;
  float* totd = (float*)p;                      p += (size_t)cb * 65536;
  __hip_bfloat16* hn = (__hip_bfloat16*)p;      p += (size_t)Mc * 1024;
  __hip_bfloat16* buf1 = (__hip_bfloat16*)p;    p += (size_t)Mc * 2048;
  __hip_bfloat16* buf2 = (__hip_bfloat16*)p;    p += (size_t)Mc * 2048;
  __hip_bfloat16* xcsbf = (__hip_bfloat16*)p;   p += (size_t)Mc * 2048;
  float* dbc = (float*)p;

  cvt_bf16_kernel<<<4096, 256, 0, stream>>>(in_proj_w, wbi, 1048576);
  cvt_bf16_kernel<<<2048, 256, 0, stream>>>(out_proj_w, wbo, 524288);
  cvt_bf16_kernel<<<128, 256, 0, stream>>>(dt_proj_w, wdtbf, 32768);
  transpose_xp_kernel<<<512, 256, 0, stream>>>(x_proj_w, wxpT);
  wcat_tail_kernel<<<1024, 256, 0, stream>>>(x_proj_w, wcat);
  // wcat rows 0..1023 = wdt @ wxp[:32]  (1024x1024, K=32)
  for (int i = 0; i < 4; ++i)
    gemm_mfma_kernel<128, 128, 6><<<dim3(8, 8), 256, 0, stream>>>(
        wdtbf + (size_t)i * 32768, 32, wxpT + (size_t)i * 32768, nullptr, 1024,
        wcat + (size_t)i * 1114112, nullptr, nullptr, 32);
  embed_kernel<<<dim3(16, 16), 256, 0, stream>>>(x, embed_w, embed_b, h);

  for (int i = 0; i < 4; ++i) {
    const float* Ai = A_log + (size_t)i * ED_ * N_;
    for (int ch = 0; ch < nchunks; ++ch) {
      float* hc = h + (size_t)ch * Mc * D_;
      rmsnorm_kernel<<<Mc / 2, 256, 0, stream>>>(hc, norm_w + i * D_, hn);
      // in_proj: col<1024 -> buf1 (xc_raw), col>=1024 -> buf2 (g = silu(z))
      gemm_mfma_kernel<128, 128, 5><<<dim3(16, Mc / 128), 256, 0, stream>>>(
          hn, D_, wbi + (size_t)i * 1048576, nullptr, 0, buf1, buf2, nullptr,
          D_);
      conv_silu_kernel<<<Mc / 2, 256, 0, stream>>>(
          buf1, conv_w + i * ED_ * DC_, conv_b + i * ED_, xcsbf);
      // fused delta+BC: delta=softplus->buf1 bf16; B,C f32 -> dbc[row*32+j]
      gemm_mfma_kernel<128, 64, 8><<<dim3(17, Mc / 128), 256, 0, stream>>>(
          xcsbf, ED_, wcat + (size_t)i * 1114112, dbc, 0, buf1, nullptr,
          dt_proj_b + i * ED_, ED_);
      scan_p1_kernel<<<dim3(4, 16, cb), 256, 0, stream>>>(
          (const unsigned short*)buf1, dbc, (const unsigned short*)xcsbf, Ai,
          S, totd);
      scan_p2_kernel<<<cb * 64, 256, 0, stream>>>(S, totd, Ai, HP);
      scan_p3_kernel<<<dim3(4, 16, cb), 256, 0, stream>>>(
          (const unsigned short*)buf1, dbc, (const unsigned short*)xcsbf, Ai,
          Dp + i * ED_, HP, (unsigned short*)buf2);
      // h += y @ out_proj^T
      gemm_mfma_kernel<128, 128, 1><<<dim3(4, Mc / 128), 256, 0, stream>>>(
          buf2, ED_, wbo + (size_t)i * 524288, hc, D_, nullptr, nullptr,
          nullptr, ED_);
    }
  }

  head_kernel<<<dim3(12, B_), 256, 0, stream>>>(h, head_w, head_b, out);
}